// Round 1
// baseline (418.980 us; speedup 1.0000x reference)
//
#include <hip/hip_runtime.h>
#include <math.h>

#define NTOK 3136           // 16*14*14 tokens
#define MT 12544            // 4 * NTOK
#define KCV 2304            // 3*3*16*16
#define THRESH 1.5f
#define LN_EPS 1e-5f

typedef short short8 __attribute__((ext_vector_type(8)));
typedef float f32x4 __attribute__((ext_vector_type(4)));

// ---------- bf16 helpers (RTNE) ----------
__device__ __forceinline__ unsigned short f2bf(float f) {
    unsigned int u = __float_as_uint(f);
    u += 0x7fffu + ((u >> 16) & 1u);
    return (unsigned short)(u >> 16);
}
__device__ __forceinline__ float bf2f(unsigned short h) {
    return __uint_as_float(((unsigned int)h) << 16);
}
__device__ __forceinline__ void async16(const void* g, void* l) {
    __builtin_amdgcn_global_load_lds((const __attribute__((address_space(1))) void*)g,
                                     (__attribute__((address_space(3))) void*)l, 16, 0, 0);
}

// ---------- wave helpers (wave = 64) ----------
__device__ __forceinline__ float wsum(float v) {
#pragma unroll
    for (int o = 32; o > 0; o >>= 1) v += __shfl_xor(v, o);
    return v;
}
__device__ __forceinline__ float wmax(float v) {
#pragma unroll
    for (int o = 32; o > 0; o >>= 1) v = fmaxf(v, __shfl_xor(v, o));
    return v;
}

// ---------- weight prep: conv_w fp32 -> hi/lo bf16, PERMUTED [k/8][e][8] ----------
// dst[(k>>3)*2048 + e*8 + (k&7)] so conv's global_load_lds staging is lane-contiguous.
__global__ __launch_bounds__(256) void split_cw_k(const float* __restrict__ cw,
    unsigned short* __restrict__ cwh, unsigned short* __restrict__ cwl)
{
    int i = blockIdx.x * 256 + threadIdx.x;     // 288 kg * 256 e = 73728
    int e = i & 255, kg = i >> 8;               // kg 0..287
    if (kg >= 288) return;
    const float4* sp = (const float4*)(cw + (size_t)e * KCV + kg * 8);
    float4 x0 = sp[0], x1 = sp[1];
    float av[8] = {x0.x, x0.y, x0.z, x0.w, x1.x, x1.y, x1.z, x1.w};
    short8 hh, ll;
#pragma unroll
    for (int j = 0; j < 8; ++j) {
        unsigned short h = f2bf(av[j]);
        hh[j] = (short)h;
        ll[j] = (short)f2bf(av[j] - bf2f(h));
    }
    size_t off = (size_t)kg * 2048 + e * 8;
    *(short8*)&cwh[off] = hh;
    *(short8*)&cwl[off] = ll;
}

// ---------- weight prep: 6 fp32 matrices -> one bf16 pool ----------
// offsets: wk 0, wv 65536, in_proj 131072 (3E*E), out_proj 327680, dense 393216, bproj 458752
__global__ __launch_bounds__(256) void cast_w_k(
    const float* __restrict__ s0, const float* __restrict__ s1, const float* __restrict__ s2,
    const float* __restrict__ s3, const float* __restrict__ s4, const float* __restrict__ s5,
    unsigned short* __restrict__ dst)
{
    int i = blockIdx.x * 256 + threadIdx.x;
    if (i >= 524288) return;
    float v;
    if      (i <  65536) v = s0[i];
    else if (i < 131072) v = s1[i - 65536];
    else if (i < 327680) v = s2[i - 131072];
    else if (i < 393216) v = s3[i - 327680];
    else if (i < 458752) v = s4[i - 393216];
    else                 v = s5[i - 458752];
    dst[i] = f2bf(v);
}

// ---------- conv as implicit GEMM on MFMA, fp32 accuracy via hi/lo bf16 split ----------
// v2: 64m x 256e per block, grid (196). A lives in REGISTERS only (lane layout ==
// MFMA A-frag layout: row w*16+(l&15), k-chunk l>>4). B double-buffered in LDS via
// global_load_lds from the permuted weight layout; ONE barrier per K-step; next-step
// A regs + B staging issued before the 48-MFMA block so the pre-barrier vmcnt drain
// lands after ~930 cyc of MFMA issue.
// Epilogue: relu+bias -> bf16 tokens; row-sum reduce -> tokmean[n] (b==0 blocks only).
__global__ __launch_bounds__(256, 1) void conv_mfma_k(
    const float* __restrict__ video, const unsigned short* __restrict__ cwh,
    const unsigned short* __restrict__ cwl, const float* __restrict__ cbias,
    float* __restrict__ tokmean, unsigned short* __restrict__ outB)
{
    __shared__ __align__(16) unsigned short Bh[16384], Bl[16384];  // 2 bufs x [kg4][e256][8]
    const int t    = threadIdx.x;
    const int lane = t & 63;
    const int w    = t >> 6;
    const int m0   = blockIdx.x * 64;
    const int l15  = lane & 15, lq = lane >> 4;

    // This lane's A row (== its MFMA A-frag row): m = m0 + w*16 + l15
    const int m = m0 + w * 16 + l15;
    const int b = m / NTOK, n = m % NTOK;
    const int d = n / 196, hw = n % 196;
    const int h = hw / 14, ww = hw % 14;
    const float* vb = video + (size_t)(b * 3) * (32 * 50176) + (h * 16) * 224 + ww * 16;
    const int dbase = 2 * d - 1;

    f32x4 acc[16] = {};
    float4 a0, a1, n0, n1;

    // --- helpers ---
    // stage B(step s) into buffer `buf`: wave w stages its k-chunk (kgg = s*4+w)
    // for all 256 e rows; fully coalesced 16B/lane from permuted layout.
#define STAGE_B(s, buf)                                                         \
    {                                                                           \
        const int kgg = (s) * 4 + w;                                            \
        const unsigned short* gh = cwh + (size_t)kgg * 2048;                    \
        const unsigned short* gl = cwl + (size_t)kgg * 2048;                    \
        unsigned short* lbh = &Bh[(buf) * 8192 + w * 2048];                     \
        unsigned short* lbl = &Bl[(buf) * 8192 + w * 2048];                     \
        _Pragma("unroll")                                                       \
        for (int ci = 0; ci < 4; ++ci) {                                        \
            async16(gh + (ci * 64 + lane) * 8, lbh + ci * 512);                 \
            async16(gl + (ci * 64 + lane) * 8, lbl + ci * 512);                 \
        }                                                                       \
    }
#define LOAD_A(s, x0, x1)                                                       \
    {                                                                           \
        const int k0  = (s) * 32 + lq * 8;                                      \
        const int c   = k0 / 768;                                               \
        const int rem = k0 - c * 768;                                           \
        const int kd  = rem >> 8;                                               \
        const int r2  = rem & 255;                                              \
        const int id  = dbase + kd;                                             \
        x0 = make_float4(0.f, 0.f, 0.f, 0.f); x1 = x0;                          \
        if (id >= 0) {                                                          \
            const float* p = vb + (size_t)c * (32 * 50176) + id * 50176 +       \
                             (r2 >> 4) * 224 + (r2 & 15);                       \
            x0 = *(const float4*)p;                                             \
            x1 = *(const float4*)(p + 4);                                       \
        }                                                                       \
    }

    // prologue: stage step 0, load A(0)
    STAGE_B(0, 0);
    LOAD_A(0, a0, a1);
    __syncthreads();

    for (int s = 0; s < 72; ++s) {
        const int cbuf = s & 1;
        // issue next-step prefetches first: they complete during the MFMA block,
        // the compiler's vmcnt(0) drain before the barrier then costs ~nothing.
        if (s + 1 < 72) {
            STAGE_B(s + 1, cbuf ^ 1);
            LOAD_A(s + 1, n0, n1);
        } else {
            n0 = make_float4(0.f, 0.f, 0.f, 0.f); n1 = n0;
        }
        // convert current A regs -> hi/lo bf16 frags (loaded one step ago: ready)
        float av[8] = {a0.x, a0.y, a0.z, a0.w, a1.x, a1.y, a1.z, a1.w};
        short8 fah, fal;
#pragma unroll
        for (int j = 0; j < 8; ++j) {
            unsigned short hh = f2bf(av[j]);
            fah[j] = (short)hh;
            fal[j] = (short)f2bf(av[j] - bf2f(hh));
        }
        const int rb = cbuf * 8192 + lq * 2048 + l15 * 8;
#pragma unroll
        for (int ct = 0; ct < 16; ++ct) {
            short8 fbh = *(const short8*)&Bh[rb + ct * 128];
            short8 fbl = *(const short8*)&Bl[rb + ct * 128];
            acc[ct] = __builtin_amdgcn_mfma_f32_16x16x32_bf16(fah, fbh, acc[ct], 0, 0, 0);
            acc[ct] = __builtin_amdgcn_mfma_f32_16x16x32_bf16(fah, fbl, acc[ct], 0, 0, 0);
            acc[ct] = __builtin_amdgcn_mfma_f32_16x16x32_bf16(fal, fbh, acc[ct], 0, 0, 0);
        }
        __syncthreads();   // drains vmcnt (prefetches) + lgkm (frag reads); flips buffer
        a0 = n0; a1 = n1;
    }
#undef STAGE_B
#undef LOAD_A

    // C/D: col(e) = lane&15, row(m) = (lane>>4)*4 + reg  [m89]
    const int rbase = m0 + w * 16 + lq * 4;
    float rsum[4] = {0.f, 0.f, 0.f, 0.f};
#pragma unroll
    for (int ct = 0; ct < 16; ++ct) {
        int e = ct * 16 + l15;
        float bias = cbias[e];
#pragma unroll
        for (int r = 0; r < 4; ++r) {
            float v = fmaxf(acc[ct][r] + bias, 0.f);
            outB[(size_t)(rbase + r) * 256 + e] = f2bf(v);
            rsum[r] += v;
        }
    }
    if (m0 < NTOK) {   // batch-0 block: emit per-token mean for the byte path
#pragma unroll
        for (int r = 0; r < 4; ++r) {
            float sv = rsum[r];
            sv += __shfl_xor(sv, 1); sv += __shfl_xor(sv, 2);
            sv += __shfl_xor(sv, 4); sv += __shfl_xor(sv, 8);
            if (l15 == 0) tokmean[rbase + r] = sv * (1.f / 256.f);
        }
    }
}

// ---------- bf16 MFMA GEMM, K=256 staged fully in LDS (one barrier) ----------
// C[m,e] = sum_k A[m,k]*W[e,k] + bias[e] (+addvec[e]) (mask m%NTOK >= *Sptr -> 0)
__global__ __launch_bounds__(256) void gemm_mfma_k(
    const unsigned short* __restrict__ A, const unsigned short* __restrict__ W,
    const float* __restrict__ bias, const float* __restrict__ addvec,
    const int* __restrict__ Sptr, float* __restrict__ outF, unsigned short* __restrict__ outB)
{
    __shared__ __align__(16) unsigned short As[16384], Bs[16384];   // 32 KB + 32 KB
    const int t = threadIdx.x, lane = t & 63, w = t >> 6;
    const int m0 = blockIdx.x * 64, e0 = blockIdx.y * 64;
    const int l15 = lane & 15, lq = lane >> 4;
    const unsigned short* ga = A + (size_t)(m0 + lane) * 256;
    const unsigned short* gb = W + (size_t)(e0 + lane) * 256;
#pragma unroll
    for (int kg = w; kg < 32; kg += 4) {
        async16(ga + kg * 8, &As[kg * 512]);
        async16(gb + kg * 8, &Bs[kg * 512]);
    }
    f32x4 acc[4] = {};
    __syncthreads();
#pragma unroll
    for (int s = 0; s < 8; ++s) {
        int kg = s * 4 + lq;
        short8 a = *(const short8*)&As[(kg * 64 + w * 16 + l15) * 8];
#pragma unroll
        for (int ct = 0; ct < 4; ++ct) {
            short8 bb = *(const short8*)&Bs[(kg * 64 + ct * 16 + l15) * 8];
            acc[ct] = __builtin_amdgcn_mfma_f32_16x16x32_bf16(a, bb, acc[ct], 0, 0, 0);
        }
    }
    int S = Sptr ? *Sptr : 0x7fffffff;
    int rbase = m0 + w * 16 + lq * 4;
#pragma unroll
    for (int ct = 0; ct < 4; ++ct) {
        int e = e0 + ct * 16 + l15;
        float bv = bias[e] + (addvec ? addvec[e] : 0.f);
#pragma unroll
        for (int r = 0; r < 4; ++r) {
            int mm = rbase + r;
            float v = acc[ct][r] + bv;
            if ((mm % NTOK) >= S) v = 0.f;
            size_t off = (size_t)mm * 256 + e;
            if (outF) outF[off] = v;
            if (outB) outB[off] = f2bf(v);
        }
    }
}

// ---------- tokmean -> byte -> entropy -> boundary (b=0 only); one wave per token ----------
__global__ __launch_bounds__(256) void boundary_k(
    const float* __restrict__ tokmean, const float* __restrict__ ent_table,
    int* __restrict__ boundary)
{
    int n    = blockIdx.x * 4 + (threadIdx.x >> 6);
    int lane = threadIdx.x & 63;
    float mean = tokmean[n];
    float bf = rintf(mean * 255.f);
    bf = fminf(fmaxf(bf, 0.f), 255.f);
    int byte = (int)bf;
    const float4 lg = reinterpret_cast<const float4*>(ent_table + byte * 256)[lane];
    float mx = wmax(fmaxf(fmaxf(lg.x, lg.y), fmaxf(lg.z, lg.w)));
    float e0 = expf(lg.x - mx), e1 = expf(lg.y - mx), e2 = expf(lg.z - mx), e3 = expf(lg.w - mx);
    float z = wsum(e0 + e1 + e2 + e3);
    float iz = 1.f / z;
    float p0 = e0 * iz, p1 = e1 * iz, p2 = e2 * iz, p3 = e3 * iz;
    float ep = -(p0 * log2f(p0 + 1e-9f) + p1 * log2f(p1 + 1e-9f) +
                 p2 * log2f(p2 + 1e-9f) + p3 * log2f(p3 + 1e-9f));
    ep = wsum(ep);
    if (lane == 0) boundary[n] = (ep > THRESH) ? 1 : 0;
}

// ---------- single-block scan: boundary -> seg_start[], S ----------
__global__ __launch_bounds__(256) void scan_k(const int* __restrict__ boundary,
    int* __restrict__ seg_start, int* __restrict__ Sptr)
{
    __shared__ int sums[256];
    const int t = threadIdx.x;
    const int CH = 13;
    int base = t * CH;
    int s = 0;
    for (int i = 0; i < CH; i++) { int n = base + i; if (n < NTOK) s += boundary[n]; }
    sums[t] = s; __syncthreads();
    for (int o = 1; o < 256; o <<= 1) {
        int v = sums[t];
        int u = (t >= o) ? sums[t - o] : 0;
        __syncthreads();
        sums[t] = v + u;
        __syncthreads();
    }
    int run = (t == 0) ? 0 : sums[t - 1];
    if (t == 0) seg_start[0] = 0;
    for (int i = 0; i < CH; i++) {
        int n = base + i;
        if (n >= NTOK) break;
        int v = boundary[n];
        if (n == NTOK - 1) { Sptr[0] = run + 1; seg_start[run + 1] = NTOK; }
        if (v && (n + 1 < NTOK)) seg_start[run + 1] = n + 1;
        run += v;
    }
}

// ---------- row LayerNorm: fp32 in -> bf16 out; one wave per row ----------
__global__ __launch_bounds__(256) void ln_bf_k(const float* __restrict__ X,
    const float* __restrict__ g, const float* __restrict__ b, unsigned short* __restrict__ Y)
{
    int row  = blockIdx.x * 4 + (threadIdx.x >> 6);
    int lane = threadIdx.x & 63;
    float4 x = reinterpret_cast<const float4*>(X + (size_t)row * 256)[lane];
    float m = wsum(x.x + x.y + x.z + x.w) * (1.f / 256.f);
    float d0 = x.x - m, d1 = x.y - m, d2 = x.z - m, d3 = x.w - m;
    float var = wsum(d0 * d0 + d1 * d1 + d2 * d2 + d3 * d3) * (1.f / 256.f);
    float inv = 1.f / sqrtf(var + LN_EPS);
    float4 g4 = reinterpret_cast<const float4*>(g)[lane];
    float4 b4 = reinterpret_cast<const float4*>(b)[lane];
    ushort4 y;
    y.x = f2bf(d0 * inv * g4.x + b4.x);
    y.y = f2bf(d1 * inv * g4.y + b4.y);
    y.z = f2bf(d2 * inv * g4.z + b4.z);
    y.w = f2bf(d3 * inv * g4.w + b4.w);
    reinterpret_cast<ushort4*>(Y + (size_t)row * 256)[lane] = y;
}

// ---------- query path: qp[256], batch-invariant, one block, fp32 ----------
__global__ __launch_bounds__(256) void query_k(
    const float* __restrict__ gq, const float* __restrict__ wq_w, const float* __restrict__ wq_b,
    const float* __restrict__ lnq_g, const float* __restrict__ lnq_b,
    const float* __restrict__ inW, const float* __restrict__ inB, float* __restrict__ qp)
{
    __shared__ float sh[256];
    __shared__ float red[256];
    const int t = threadIdx.x;
    float acc = wq_b[t];
    for (int j = 0; j < 256; j++) acc += gq[j] * wq_w[t * 256 + j];
    red[t] = acc; __syncthreads();
    for (int o = 128; o > 0; o >>= 1) { if (t < o) red[t] += red[t + o]; __syncthreads(); }
    float m = red[0] * (1.f / 256.f);
    __syncthreads();
    float d = acc - m;
    red[t] = d * d; __syncthreads();
    for (int o = 128; o > 0; o >>= 1) { if (t < o) red[t] += red[t + o]; __syncthreads(); }
    float inv = 1.f / sqrtf(red[0] * (1.f / 256.f) + LN_EPS);
    sh[t] = d * inv * lnq_g[t] + lnq_b[t];
    __syncthreads();
    float a2 = inB[t];
    for (int j = 0; j < 256; j++) a2 += sh[j] * inW[t * 256 + j];
    qp[t] = a2 * 0.125f;
}

// ---------- scores[n,b,h] = dot(qp[h], kp[b,n,h]); kp bf16; one wave per (b,n) ----------
__global__ __launch_bounds__(256) void scores_k(const unsigned short* __restrict__ kp,
    const float* __restrict__ qp, float* __restrict__ sc)
{
    int idx  = blockIdx.x * 4 + (threadIdx.x >> 6);   // b*NTOK + n
    int lane = threadIdx.x & 63;
    ushort4 k4 = reinterpret_cast<const ushort4*>(kp + (size_t)idx * 256)[lane];
    float4 q4 = reinterpret_cast<const float4*>(qp)[lane];
    float p = bf2f(k4.x) * q4.x + bf2f(k4.y) * q4.y + bf2f(k4.z) * q4.z + bf2f(k4.w) * q4.w;
    p += __shfl_xor(p, 1); p += __shfl_xor(p, 2);
    p += __shfl_xor(p, 4); p += __shfl_xor(p, 8);
    if ((lane & 15) == 0) {
        int b = idx / NTOK, n = idx % NTOK;
        int h = lane >> 4;
        sc[(b * 4 + h) * NTOK + n] = p;
    }
}

// ---------- segment softmax-attention; vp bf16 in, attn bf16 out ----------
__global__ __launch_bounds__(256) void attn_bf_k(const float* __restrict__ sc,
    const unsigned short* __restrict__ vp, const int* __restrict__ seg_start,
    const int* __restrict__ Sptr, unsigned short* __restrict__ attn)
{
    int s    = blockIdx.x;
    int b    = threadIdx.x >> 6;
    int lane = threadIdx.x & 63;
    unsigned short* orow = attn + ((size_t)b * NTOK + s) * 256;
    int S = *Sptr;
    if (s >= S) {
#pragma unroll
        for (int h = 0; h < 4; h++) orow[h * 64 + lane] = 0;
        return;
    }
    int st = seg_start[s], en = seg_start[s + 1];
    for (int h = 0; h < 4; h++) {
        const float* scr = sc + (b * 4 + h) * NTOK;
        float m = -1e30f;
        for (int n = st; n < en; n++) m = fmaxf(m, scr[n]);
        float den = 0.f, acc = 0.f;
        for (int n = st; n < en; n++) {
            float wgt = expf(scr[n] - m);
            den += wgt;
            acc += wgt * bf2f(vp[((size_t)b * NTOK + n) * 256 + h * 64 + lane]);
        }
        orow[h * 64 + lane] = f2bf(acc / den);
    }
}

extern "C" void kernel_launch(void* const* d_in, const int* in_sizes, int n_in,
                              void* d_out, int out_size, void* d_ws, size_t ws_size,
                              hipStream_t stream)
{
    const float* video      = (const float*)d_in[0];
    const float* conv_w     = (const float*)d_in[1];
    const float* conv_b     = (const float*)d_in[2];
    const float* wq_w       = (const float*)d_in[3];
    const float* wq_b       = (const float*)d_in[4];
    const float* wk_w       = (const float*)d_in[5];
    const float* wk_b       = (const float*)d_in[6];
    const float* wv_w       = (const float*)d_in[7];
    const float* wv_b       = (const float*)d_in[8];
    const float* lnq_g      = (const float*)d_in[9];
    const float* lnq_b      = (const float*)d_in[10];
    const float* lnk_g      = (const float*)d_in[11];
    const float* lnk_b      = (const float*)d_in[12];
    const float* lnv_g      = (const float*)d_in[13];
    const float* lnv_b      = (const float*)d_in[14];
    const float* in_proj_w  = (const float*)d_in[15];
    const float* in_proj_b  = (const float*)d_in[16];
    const float* out_proj_w = (const float*)d_in[17];
    const float* out_proj_b = (const float*)d_in[18];
    const float* dense_w    = (const float*)d_in[19];
    const float* dense_b    = (const float*)d_in[20];
    const float* bproj_w    = (const float*)d_in[21];
    const float* bproj_b    = (const float*)d_in[22];
    const float* group_q    = (const float*)d_in[23];
    const float* ent_table  = (const float*)d_in[24];
    float* out = (float*)d_out;

    // ---- workspace layout (~49 MB, unchanged offsets) ----
    float* W1f = (float*)d_ws;                         // now: tokmean[NTOK] (rest unused)
    float* P   = W1f + (size_t)MT * 256;               // fp32 pre-LN buffer
    unsigned short* B1 = (unsigned short*)(P + (size_t)MT * 256);  // tokens_b16 / attn_b16
    unsigned short* B2 = B1 + (size_t)MT * 256;        // kln/vln/o1
    unsigned short* B3 = B2 + (size_t)MT * 256;        // kp/vp/o2
    unsigned short* cwh = B3 + (size_t)MT * 256;       // conv weights hi (permuted)
    unsigned short* cwl = cwh + 256 * KCV;             // conv weights lo (permuted)
    unsigned short* wpool = cwl + 256 * KCV;           // 524288 bf16 weights
    float* sc = (float*)(wpool + 524288);              // scores [B*NH][NTOK]
    float* qp = sc + 16 * NTOK;
    int* boundary  = (int*)(qp + 256);
    int* seg_start = boundary + NTOK;
    int* Sp        = seg_start + (NTOK + 1);

    const unsigned short* wkb    = wpool;
    const unsigned short* wvb    = wpool + 65536;
    const unsigned short* inpb   = wpool + 131072;     // 3E x E
    const unsigned short* outpb  = wpool + 327680;
    const unsigned short* denseb = wpool + 393216;
    const unsigned short* bprojb = wpool + 458752;

    dim3 gG(196, 4), blk(256);
    split_cw_k<<<dim3(288), blk, 0, stream>>>(conv_w, cwh, cwl);
    cast_w_k<<<dim3(2048), blk, 0, stream>>>(wk_w, wv_w, in_proj_w, out_proj_w,
                                             dense_w, bproj_w, wpool);
    conv_mfma_k<<<dim3(196), blk, 0, stream>>>(video, cwh, cwl, conv_b, W1f, B1);
    boundary_k<<<dim3(NTOK / 4), blk, 0, stream>>>(W1f, ent_table, boundary);
    scan_k<<<dim3(1), blk, 0, stream>>>(boundary, seg_start, Sp);
    query_k<<<dim3(1), blk, 0, stream>>>(group_q, wq_w, wq_b, lnq_g, lnq_b,
                                         in_proj_w, in_proj_b, qp);
    // K path
    gemm_mfma_k<<<gG, blk, 0, stream>>>(B1, wkb, wk_b, nullptr, nullptr, P, nullptr);
    ln_bf_k<<<dim3(MT / 4), blk, 0, stream>>>(P, lnk_g, lnk_b, B2);
    gemm_mfma_k<<<gG, blk, 0, stream>>>(B2, inpb + 65536, in_proj_b + 256,
                                        nullptr, nullptr, nullptr, B3);   // kp
    scores_k<<<dim3(MT / 4), blk, 0, stream>>>(B3, qp, sc);
    // V path
    gemm_mfma_k<<<gG, blk, 0, stream>>>(B1, wvb, wv_b, nullptr, nullptr, P, nullptr);
    ln_bf_k<<<dim3(MT / 4), blk, 0, stream>>>(P, lnv_g, lnv_b, B2);
    gemm_mfma_k<<<gG, blk, 0, stream>>>(B2, inpb + 131072, in_proj_b + 512,
                                        nullptr, nullptr, nullptr, B3);   // vp
    // segment attention
    attn_bf_k<<<dim3(NTOK), blk, 0, stream>>>(sc, B3, seg_start, Sp, B1);
    // tail projections
    gemm_mfma_k<<<gG, blk, 0, stream>>>(B1, outpb, out_proj_b, nullptr, nullptr, nullptr, B2);
    gemm_mfma_k<<<gG, blk, 0, stream>>>(B2, denseb, dense_b, group_q, nullptr, nullptr, B3);
    gemm_mfma_k<<<gG, blk, 0, stream>>>(B3, bprojb, bproj_b, nullptr, Sp, out, nullptr);
}

// Round 2
// 388.348 us; speedup vs baseline: 1.0789x; 1.0789x over previous
//
#include <hip/hip_runtime.h>
#include <hip/hip_bf16.h>
#include <math.h>

#define NTOK 3136           // 16*14*14 tokens
#define MT 12544            // 4 * NTOK
#define KCV 2304            // 3*3*16*16
#define THRESH 1.5f
#define LN_EPS 1e-5f

typedef short short8 __attribute__((ext_vector_type(8)));
typedef float f32x4 __attribute__((ext_vector_type(4)));

// ---------- bf16 helpers ----------
__device__ __forceinline__ unsigned short f2bf(float f) {   // manual RTNE (cold paths)
    unsigned int u = __float_as_uint(f);
    u += 0x7fffu + ((u >> 16) & 1u);
    return (unsigned short)(u >> 16);
}
__device__ __forceinline__ float bf2f(unsigned short h) {
    return __uint_as_float(((unsigned int)h) << 16);
}
// HW packed cvt (v_cvt_pk_bf16_f32, RTNE): low16 = bf(x0), high16 = bf(x1)
__device__ __forceinline__ unsigned int cvt_pk_bf16(float x0, float x1) {
    union { __hip_bfloat162 h; unsigned int u; } cv;
    cv.h = __float22bfloat162_rn(make_float2(x0, x1));
    return cv.u;
}
__device__ __forceinline__ void async16(const void* g, void* l) {
    __builtin_amdgcn_global_load_lds((const __attribute__((address_space(1))) void*)g,
                                     (__attribute__((address_space(3))) void*)l, 16, 0, 0);
}

// ---------- wave helpers (wave = 64) ----------
__device__ __forceinline__ float wsum(float v) {
#pragma unroll
    for (int o = 32; o > 0; o >>= 1) v += __shfl_xor(v, o);
    return v;
}
__device__ __forceinline__ float wmax(float v) {
#pragma unroll
    for (int o = 32; o > 0; o >>= 1) v = fmaxf(v, __shfl_xor(v, o));
    return v;
}

// ---------- weight prep: conv_w fp32 -> hi/lo bf16, PERMUTED [k/8][e][8] ----------
// dst[(k>>3)*2048 + e*8 + (k&7)] so conv's global_load_lds staging is lane-contiguous.
__global__ __launch_bounds__(256) void split_cw_k(const float* __restrict__ cw,
    unsigned short* __restrict__ cwh, unsigned short* __restrict__ cwl)
{
    int i = blockIdx.x * 256 + threadIdx.x;     // 288 kg * 256 e = 73728
    int e = i & 255, kg = i >> 8;               // kg 0..287
    if (kg >= 288) return;
    const float4* sp = (const float4*)(cw + (size_t)e * KCV + kg * 8);
    float4 x0 = sp[0], x1 = sp[1];
    float av[8] = {x0.x, x0.y, x0.z, x0.w, x1.x, x1.y, x1.z, x1.w};
    short8 hh, ll;
#pragma unroll
    for (int j = 0; j < 8; ++j) {
        unsigned short h = f2bf(av[j]);
        hh[j] = (short)h;
        ll[j] = (short)f2bf(av[j] - bf2f(h));
    }
    size_t off = (size_t)kg * 2048 + e * 8;
    *(short8*)&cwh[off] = hh;
    *(short8*)&cwl[off] = ll;
}

// ---------- weight prep: 6 fp32 matrices -> one bf16 pool ----------
// offsets: wk 0, wv 65536, in_proj 131072 (3E*E), out_proj 327680, dense 393216, bproj 458752
__global__ __launch_bounds__(256) void cast_w_k(
    const float* __restrict__ s0, const float* __restrict__ s1, const float* __restrict__ s2,
    const float* __restrict__ s3, const float* __restrict__ s4, const float* __restrict__ s5,
    unsigned short* __restrict__ dst)
{
    int i = blockIdx.x * 256 + threadIdx.x;
    if (i >= 524288) return;
    float v;
    if      (i <  65536) v = s0[i];
    else if (i < 131072) v = s1[i - 65536];
    else if (i < 327680) v = s2[i - 131072];
    else if (i < 393216) v = s3[i - 327680];
    else if (i < 458752) v = s4[i - 393216];
    else                 v = s5[i - 458752];
    dst[i] = f2bf(v);
}

// ---------- conv as implicit GEMM on MFMA, fp32 accuracy via hi/lo bf16 split ----------
// v3: 64m x 64e per block, grid (196,4) = 784 blocks -> ~3 blocks/CU (TLP restores
// latency hiding). A in REGISTERS (lane layout == MFMA A-frag), prefetch depth 2.
// B hi/lo double-buffered in 16KB LDS via global_load_lds from permuted layout;
// one barrier per K-step. HW v_cvt_pk_bf16_f32 for the A hi/lo split.
// Epilogue: relu+bias -> bf16 tokens; partial row-sums -> tokmean4[eb][n] (b==0).
__global__ __launch_bounds__(256) void conv_mfma_k(
    const float* __restrict__ video, const unsigned short* __restrict__ cwh,
    const unsigned short* __restrict__ cwl, const float* __restrict__ cbias,
    float* __restrict__ tokmean4, unsigned short* __restrict__ outB)
{
    __shared__ __align__(16) unsigned short Bh[4096], Bl[4096];  // 2 bufs x [kg4][e64][8]
    const int t    = threadIdx.x;
    const int lane = t & 63;
    const int w    = t >> 6;
    const int m0   = blockIdx.x * 64;
    const int e0   = blockIdx.y * 64;
    const int l15  = lane & 15, lq = lane >> 4;

    // This lane's A row (== its MFMA A-frag row): m = m0 + w*16 + l15
    const int m = m0 + w * 16 + l15;
    const int b = m / NTOK, n = m % NTOK;
    const int d = n / 196, hw = n % 196;
    const int h = hw / 14, ww = hw % 14;
    const float* vb = video + (size_t)(b * 3) * (32 * 50176) + (h * 16) * 224 + ww * 16;
    const int dbase = 2 * d - 1;

    f32x4 acc[4] = {};
    float4 a0, a1, n0, n1, p0, p1;

    // stage B(step s) into buffer `buf`: wave w stages k-chunk kgg = s*4+w for the
    // block's 64 e-rows; per-lane global src (coalesced 1KB), wave-uniform LDS dest.
#define STAGE_B(s, buf)                                                              \
    {                                                                                \
        const int kgg = (s) * 4 + w;                                                 \
        async16(cwh + (size_t)kgg * 2048 + (e0 + lane) * 8,                          \
                &Bh[(buf) * 2048 + w * 512]);                                        \
        async16(cwl + (size_t)kgg * 2048 + (e0 + lane) * 8,                          \
                &Bl[(buf) * 2048 + w * 512]);                                        \
    }
#define LOAD_A(s, x0, x1)                                                            \
    {                                                                                \
        const int k0  = (s) * 32 + lq * 8;                                           \
        const int c   = k0 / 768;                                                    \
        const int rem = k0 - c * 768;                                                \
        const int kd  = rem >> 8;                                                    \
        const int r2  = rem & 255;                                                   \
        const int id  = dbase + kd;                                                  \
        x0 = make_float4(0.f, 0.f, 0.f, 0.f); x1 = x0;                               \
        if (id >= 0) {                                                               \
            const float* p = vb + (size_t)c * (32 * 50176) + id * 50176 +            \
                             (r2 >> 4) * 224 + (r2 & 15);                            \
            x0 = *(const float4*)p;                                                  \
            x1 = *(const float4*)(p + 4);                                            \
        }                                                                            \
    }

    // prologue: stage step 0; A prefetch depth 2
    STAGE_B(0, 0);
    LOAD_A(0, a0, a1);
    LOAD_A(1, n0, n1);
    __syncthreads();

    for (int s = 0; s < 72; ++s) {
        const int cbuf = s & 1;
        if (s + 1 < 72) STAGE_B(s + 1, cbuf ^ 1);
        if (s + 2 < 72) { LOAD_A(s + 2, p0, p1); }
        else            { p0 = make_float4(0.f, 0.f, 0.f, 0.f); p1 = p0; }
        // convert cur A regs (loaded 2 steps ago: ready) -> hi/lo packed bf16 frags
        float av[8] = {a0.x, a0.y, a0.z, a0.w, a1.x, a1.y, a1.z, a1.w};
        unsigned int ph[4], pl[4];
#pragma unroll
        for (int j = 0; j < 4; ++j) {
            float x0 = av[2 * j], x1 = av[2 * j + 1];
            unsigned int hu = cvt_pk_bf16(x0, x1);
            float r0 = x0 - __uint_as_float(hu << 16);
            float r1 = x1 - __uint_as_float(hu & 0xffff0000u);
            ph[j] = hu;
            pl[j] = cvt_pk_bf16(r0, r1);
        }
        int4 phv = make_int4(ph[0], ph[1], ph[2], ph[3]);
        int4 plv = make_int4(pl[0], pl[1], pl[2], pl[3]);
        short8 fah = *(short8*)&phv;
        short8 fal = *(short8*)&plv;
        const int rb = cbuf * 2048 + lq * 512 + l15 * 8;
#pragma unroll
        for (int ct = 0; ct < 4; ++ct) {
            short8 fbh = *(const short8*)&Bh[rb + ct * 128];
            short8 fbl = *(const short8*)&Bl[rb + ct * 128];
            acc[ct] = __builtin_amdgcn_mfma_f32_16x16x32_bf16(fah, fbh, acc[ct], 0, 0, 0);
            acc[ct] = __builtin_amdgcn_mfma_f32_16x16x32_bf16(fah, fbl, acc[ct], 0, 0, 0);
            acc[ct] = __builtin_amdgcn_mfma_f32_16x16x32_bf16(fal, fbh, acc[ct], 0, 0, 0);
        }
        __syncthreads();   // drains vmcnt (prefetches) + lgkm (frag reads); flips buffer
        a0 = n0; a1 = n1; n0 = p0; n1 = p1;
    }
#undef STAGE_B
#undef LOAD_A

    // C/D: col(e) = lane&15, row(m) = (lane>>4)*4 + reg  [m89]
    const int rbase = m0 + w * 16 + lq * 4;
    float rsum[4] = {0.f, 0.f, 0.f, 0.f};
#pragma unroll
    for (int ct = 0; ct < 4; ++ct) {
        int e = e0 + ct * 16 + l15;
        float bias = cbias[e];
#pragma unroll
        for (int r = 0; r < 4; ++r) {
            float v = fmaxf(acc[ct][r] + bias, 0.f);
            outB[(size_t)(rbase + r) * 256 + e] = f2bf(v);
            rsum[r] += v;
        }
    }
    if (m0 < NTOK) {   // batch-0 block: emit 64-e partial sum for the byte path
#pragma unroll
        for (int r = 0; r < 4; ++r) {
            float sv = rsum[r];
            sv += __shfl_xor(sv, 1); sv += __shfl_xor(sv, 2);
            sv += __shfl_xor(sv, 4); sv += __shfl_xor(sv, 8);
            if (l15 == 0) tokmean4[(size_t)blockIdx.y * NTOK + rbase + r] = sv;
        }
    }
}

// ---------- bf16 MFMA GEMM, K=256 staged fully in LDS (one barrier) ----------
// C[m,e] = sum_k A[m,k]*W[e,k] + bias[e] (+addvec[e]) (mask m%NTOK >= *Sptr -> 0)
__global__ __launch_bounds__(256) void gemm_mfma_k(
    const unsigned short* __restrict__ A, const unsigned short* __restrict__ W,
    const float* __restrict__ bias, const float* __restrict__ addvec,
    const int* __restrict__ Sptr, float* __restrict__ outF, unsigned short* __restrict__ outB)
{
    __shared__ __align__(16) unsigned short As[16384], Bs[16384];   // 32 KB + 32 KB
    const int t = threadIdx.x, lane = t & 63, w = t >> 6;
    const int m0 = blockIdx.x * 64, e0 = blockIdx.y * 64;
    const int l15 = lane & 15, lq = lane >> 4;
    const unsigned short* ga = A + (size_t)(m0 + lane) * 256;
    const unsigned short* gb = W + (size_t)(e0 + lane) * 256;
#pragma unroll
    for (int kg = w; kg < 32; kg += 4) {
        async16(ga + kg * 8, &As[kg * 512]);
        async16(gb + kg * 8, &Bs[kg * 512]);
    }
    f32x4 acc[4] = {};
    __syncthreads();
#pragma unroll
    for (int s = 0; s < 8; ++s) {
        int kg = s * 4 + lq;
        short8 a = *(const short8*)&As[(kg * 64 + w * 16 + l15) * 8];
#pragma unroll
        for (int ct = 0; ct < 4; ++ct) {
            short8 bb = *(const short8*)&Bs[(kg * 64 + ct * 16 + l15) * 8];
            acc[ct] = __builtin_amdgcn_mfma_f32_16x16x32_bf16(a, bb, acc[ct], 0, 0, 0);
        }
    }
    int S = Sptr ? *Sptr : 0x7fffffff;
    int rbase = m0 + w * 16 + lq * 4;
#pragma unroll
    for (int ct = 0; ct < 4; ++ct) {
        int e = e0 + ct * 16 + l15;
        float bv = bias[e] + (addvec ? addvec[e] : 0.f);
#pragma unroll
        for (int r = 0; r < 4; ++r) {
            int mm = rbase + r;
            float v = acc[ct][r] + bv;
            if ((mm % NTOK) >= S) v = 0.f;
            size_t off = (size_t)mm * 256 + e;
            if (outF) outF[off] = v;
            if (outB) outB[off] = f2bf(v);
        }
    }
}

// ---------- tokmean4 -> byte -> entropy -> boundary (b=0 only); one wave per token ----------
__global__ __launch_bounds__(256) void boundary_k(
    const float* __restrict__ tokmean4, const float* __restrict__ ent_table,
    int* __restrict__ boundary)
{
    int n    = blockIdx.x * 4 + (threadIdx.x >> 6);
    int lane = threadIdx.x & 63;
    float s0 = tokmean4[n];
    float s1 = tokmean4[NTOK + n];
    float s2 = tokmean4[2 * NTOK + n];
    float s3 = tokmean4[3 * NTOK + n];
    float mean = ((s0 + s1) + (s2 + s3)) * (1.f / 256.f);   // deterministic order
    float bf = rintf(mean * 255.f);
    bf = fminf(fmaxf(bf, 0.f), 255.f);
    int byte = (int)bf;
    const float4 lg = reinterpret_cast<const float4*>(ent_table + byte * 256)[lane];
    float mx = wmax(fmaxf(fmaxf(lg.x, lg.y), fmaxf(lg.z, lg.w)));
    float e0 = expf(lg.x - mx), e1 = expf(lg.y - mx), e2 = expf(lg.z - mx), e3 = expf(lg.w - mx);
    float z = wsum(e0 + e1 + e2 + e3);
    float iz = 1.f / z;
    float p0 = e0 * iz, p1 = e1 * iz, p2 = e2 * iz, p3 = e3 * iz;
    float ep = -(p0 * log2f(p0 + 1e-9f) + p1 * log2f(p1 + 1e-9f) +
                 p2 * log2f(p2 + 1e-9f) + p3 * log2f(p3 + 1e-9f));
    ep = wsum(ep);
    if (lane == 0) boundary[n] = (ep > THRESH) ? 1 : 0;
}

// ---------- single-block scan: boundary -> seg_start[], S ----------
__global__ __launch_bounds__(256) void scan_k(const int* __restrict__ boundary,
    int* __restrict__ seg_start, int* __restrict__ Sptr)
{
    __shared__ int sums[256];
    const int t = threadIdx.x;
    const int CH = 13;
    int base = t * CH;
    int s = 0;
    for (int i = 0; i < CH; i++) { int n = base + i; if (n < NTOK) s += boundary[n]; }
    sums[t] = s; __syncthreads();
    for (int o = 1; o < 256; o <<= 1) {
        int v = sums[t];
        int u = (t >= o) ? sums[t - o] : 0;
        __syncthreads();
        sums[t] = v + u;
        __syncthreads();
    }
    int run = (t == 0) ? 0 : sums[t - 1];
    if (t == 0) seg_start[0] = 0;
    for (int i = 0; i < CH; i++) {
        int n = base + i;
        if (n >= NTOK) break;
        int v = boundary[n];
        if (n == NTOK - 1) { Sptr[0] = run + 1; seg_start[run + 1] = NTOK; }
        if (v && (n + 1 < NTOK)) seg_start[run + 1] = n + 1;
        run += v;
    }
}

// ---------- row LayerNorm: fp32 in -> bf16 out; one wave per row ----------
__global__ __launch_bounds__(256) void ln_bf_k(const float* __restrict__ X,
    const float* __restrict__ g, const float* __restrict__ b, unsigned short* __restrict__ Y)
{
    int row  = blockIdx.x * 4 + (threadIdx.x >> 6);
    int lane = threadIdx.x & 63;
    float4 x = reinterpret_cast<const float4*>(X + (size_t)row * 256)[lane];
    float m = wsum(x.x + x.y + x.z + x.w) * (1.f / 256.f);
    float d0 = x.x - m, d1 = x.y - m, d2 = x.z - m, d3 = x.w - m;
    float var = wsum(d0 * d0 + d1 * d1 + d2 * d2 + d3 * d3) * (1.f / 256.f);
    float inv = 1.f / sqrtf(var + LN_EPS);
    float4 g4 = reinterpret_cast<const float4*>(g)[lane];
    float4 b4 = reinterpret_cast<const float4*>(b)[lane];
    ushort4 y;
    y.x = f2bf(d0 * inv * g4.x + b4.x);
    y.y = f2bf(d1 * inv * g4.y + b4.y);
    y.z = f2bf(d2 * inv * g4.z + b4.z);
    y.w = f2bf(d3 * inv * g4.w + b4.w);
    reinterpret_cast<ushort4*>(Y + (size_t)row * 256)[lane] = y;
}

// ---------- query path: qp[256], batch-invariant, one block, fp32 ----------
__global__ __launch_bounds__(256) void query_k(
    const float* __restrict__ gq, const float* __restrict__ wq_w, const float* __restrict__ wq_b,
    const float* __restrict__ lnq_g, const float* __restrict__ lnq_b,
    const float* __restrict__ inW, const float* __restrict__ inB, float* __restrict__ qp)
{
    __shared__ float sh[256];
    __shared__ float red[256];
    const int t = threadIdx.x;
    float acc = wq_b[t];
    for (int j = 0; j < 256; j++) acc += gq[j] * wq_w[t * 256 + j];
    red[t] = acc; __syncthreads();
    for (int o = 128; o > 0; o >>= 1) { if (t < o) red[t] += red[t + o]; __syncthreads(); }
    float m = red[0] * (1.f / 256.f);
    __syncthreads();
    float d = acc - m;
    red[t] = d * d; __syncthreads();
    for (int o = 128; o > 0; o >>= 1) { if (t < o) red[t] += red[t + o]; __syncthreads(); }
    float inv = 1.f / sqrtf(red[0] * (1.f / 256.f) + LN_EPS);
    sh[t] = d * inv * lnq_g[t] + lnq_b[t];
    __syncthreads();
    float a2 = inB[t];
    for (int j = 0; j < 256; j++) a2 += sh[j] * inW[t * 256 + j];
    qp[t] = a2 * 0.125f;
}

// ---------- scores[n,b,h] = dot(qp[h], kp[b,n,h]); kp bf16; one wave per (b,n) ----------
__global__ __launch_bounds__(256) void scores_k(const unsigned short* __restrict__ kp,
    const float* __restrict__ qp, float* __restrict__ sc)
{
    int idx  = blockIdx.x * 4 + (threadIdx.x >> 6);   // b*NTOK + n
    int lane = threadIdx.x & 63;
    ushort4 k4 = reinterpret_cast<const ushort4*>(kp + (size_t)idx * 256)[lane];
    float4 q4 = reinterpret_cast<const float4*>(qp)[lane];
    float p = bf2f(k4.x) * q4.x + bf2f(k4.y) * q4.y + bf2f(k4.z) * q4.z + bf2f(k4.w) * q4.w;
    p += __shfl_xor(p, 1); p += __shfl_xor(p, 2);
    p += __shfl_xor(p, 4); p += __shfl_xor(p, 8);
    if ((lane & 15) == 0) {
        int b = idx / NTOK, n = idx % NTOK;
        int h = lane >> 4;
        sc[(b * 4 + h) * NTOK + n] = p;
    }
}

// ---------- segment softmax-attention; vp bf16 in, attn bf16 out ----------
__global__ __launch_bounds__(256) void attn_bf_k(const float* __restrict__ sc,
    const unsigned short* __restrict__ vp, const int* __restrict__ seg_start,
    const int* __restrict__ Sptr, unsigned short* __restrict__ attn)
{
    int s    = blockIdx.x;
    int b    = threadIdx.x >> 6;
    int lane = threadIdx.x & 63;
    unsigned short* orow = attn + ((size_t)b * NTOK + s) * 256;
    int S = *Sptr;
    if (s >= S) {
#pragma unroll
        for (int h = 0; h < 4; h++) orow[h * 64 + lane] = 0;
        return;
    }
    int st = seg_start[s], en = seg_start[s + 1];
    for (int h = 0; h < 4; h++) {
        const float* scr = sc + (b * 4 + h) * NTOK;
        float m = -1e30f;
        for (int n = st; n < en; n++) m = fmaxf(m, scr[n]);
        float den = 0.f, acc = 0.f;
        for (int n = st; n < en; n++) {
            float wgt = expf(scr[n] - m);
            den += wgt;
            acc += wgt * bf2f(vp[((size_t)b * NTOK + n) * 256 + h * 64 + lane]);
        }
        orow[h * 64 + lane] = f2bf(acc / den);
    }
}

extern "C" void kernel_launch(void* const* d_in, const int* in_sizes, int n_in,
                              void* d_out, int out_size, void* d_ws, size_t ws_size,
                              hipStream_t stream)
{
    const float* video      = (const float*)d_in[0];
    const float* conv_w     = (const float*)d_in[1];
    const float* conv_b     = (const float*)d_in[2];
    const float* wq_w       = (const float*)d_in[3];
    const float* wq_b       = (const float*)d_in[4];
    const float* wk_w       = (const float*)d_in[5];
    const float* wk_b       = (const float*)d_in[6];
    const float* wv_w       = (const float*)d_in[7];
    const float* wv_b       = (const float*)d_in[8];
    const float* lnq_g      = (const float*)d_in[9];
    const float* lnq_b      = (const float*)d_in[10];
    const float* lnk_g      = (const float*)d_in[11];
    const float* lnk_b      = (const float*)d_in[12];
    const float* lnv_g      = (const float*)d_in[13];
    const float* lnv_b      = (const float*)d_in[14];
    const float* in_proj_w  = (const float*)d_in[15];
    const float* in_proj_b  = (const float*)d_in[16];
    const float* out_proj_w = (const float*)d_in[17];
    const float* out_proj_b = (const float*)d_in[18];
    const float* dense_w    = (const float*)d_in[19];
    const float* dense_b    = (const float*)d_in[20];
    const float* bproj_w    = (const float*)d_in[21];
    const float* bproj_b    = (const float*)d_in[22];
    const float* group_q    = (const float*)d_in[23];
    const float* ent_table  = (const float*)d_in[24];
    float* out = (float*)d_out;

    // ---- workspace layout (~49 MB, unchanged offsets) ----
    float* W1f = (float*)d_ws;                         // tokmean4[4][NTOK] (rest unused)
    float* P   = W1f + (size_t)MT * 256;               // fp32 pre-LN buffer
    unsigned short* B1 = (unsigned short*)(P + (size_t)MT * 256);  // tokens_b16 / attn_b16
    unsigned short* B2 = B1 + (size_t)MT * 256;        // kln/vln/o1
    unsigned short* B3 = B2 + (size_t)MT * 256;        // kp/vp/o2
    unsigned short* cwh = B3 + (size_t)MT * 256;       // conv weights hi (permuted)
    unsigned short* cwl = cwh + 256 * KCV;             // conv weights lo (permuted)
    unsigned short* wpool = cwl + 256 * KCV;           // 524288 bf16 weights
    float* sc = (float*)(wpool + 524288);              // scores [B*NH][NTOK]
    float* qp = sc + 16 * NTOK;
    int* boundary  = (int*)(qp + 256);
    int* seg_start = boundary + NTOK;
    int* Sp        = seg_start + (NTOK + 1);

    const unsigned short* wkb    = wpool;
    const unsigned short* wvb    = wpool + 65536;
    const unsigned short* inpb   = wpool + 131072;     // 3E x E
    const unsigned short* outpb  = wpool + 327680;
    const unsigned short* denseb = wpool + 393216;
    const unsigned short* bprojb = wpool + 458752;

    dim3 gG(196, 4), blk(256);
    split_cw_k<<<dim3(288), blk, 0, stream>>>(conv_w, cwh, cwl);
    cast_w_k<<<dim3(2048), blk, 0, stream>>>(wk_w, wv_w, in_proj_w, out_proj_w,
                                             dense_w, bproj_w, wpool);
    conv_mfma_k<<<dim3(196, 4), blk, 0, stream>>>(video, cwh, cwl, conv_b, W1f, B1);
    boundary_k<<<dim3(NTOK / 4), blk, 0, stream>>>(W1f, ent_table, boundary);
    scan_k<<<dim3(1), blk, 0, stream>>>(boundary, seg_start, Sp);
    query_k<<<dim3(1), blk, 0, stream>>>(group_q, wq_w, wq_b, lnq_g, lnq_b,
                                         in_proj_w, in_proj_b, qp);
    // K path
    gemm_mfma_k<<<gG, blk, 0, stream>>>(B1, wkb, wk_b, nullptr, nullptr, P, nullptr);
    ln_bf_k<<<dim3(MT / 4), blk, 0, stream>>>(P, lnk_g, lnk_b, B2);
    gemm_mfma_k<<<gG, blk, 0, stream>>>(B2, inpb + 65536, in_proj_b + 256,
                                        nullptr, nullptr, nullptr, B3);   // kp
    scores_k<<<dim3(MT / 4), blk, 0, stream>>>(B3, qp, sc);
    // V path
    gemm_mfma_k<<<gG, blk, 0, stream>>>(B1, wvb, wv_b, nullptr, nullptr, P, nullptr);
    ln_bf_k<<<dim3(MT / 4), blk, 0, stream>>>(P, lnv_g, lnv_b, B2);
    gemm_mfma_k<<<gG, blk, 0, stream>>>(B2, inpb + 131072, in_proj_b + 512,
                                        nullptr, nullptr, nullptr, B3);   // vp
    // segment attention
    attn_bf_k<<<dim3(NTOK), blk, 0, stream>>>(sc, B3, seg_start, Sp, B1);
    // tail projections
    gemm_mfma_k<<<gG, blk, 0, stream>>>(B1, outpb, out_proj_b, nullptr, nullptr, nullptr, B2);
    gemm_mfma_k<<<gG, blk, 0, stream>>>(B2, denseb, dense_b, group_q, nullptr, nullptr, B3);
    gemm_mfma_k<<<gG, blk, 0, stream>>>(B3, bprojb, bproj_b, nullptr, Sp, out, nullptr);
}

// Round 3
// 354.211 us; speedup vs baseline: 1.1829x; 1.0964x over previous
//
#include <hip/hip_runtime.h>
#include <hip/hip_bf16.h>
#include <math.h>

#define NTOK 3136           // 16*14*14 tokens
#define MT 12544            // 4 * NTOK
#define KCV 2304            // 3*3*16*16
#define THRESH 1.5f
#define LN_EPS 1e-5f

typedef short short8 __attribute__((ext_vector_type(8)));
typedef float f32x4 __attribute__((ext_vector_type(4)));

// ---------- bf16 helpers ----------
__device__ __forceinline__ unsigned short f2bf(float f) {   // manual RTNE (cold paths)
    unsigned int u = __float_as_uint(f);
    u += 0x7fffu + ((u >> 16) & 1u);
    return (unsigned short)(u >> 16);
}
__device__ __forceinline__ float bf2f(unsigned short h) {
    return __uint_as_float(((unsigned int)h) << 16);
}
// HW packed cvt (v_cvt_pk_bf16_f32, RTNE): low16 = bf(x0), high16 = bf(x1)
__device__ __forceinline__ unsigned int cvt_pk_bf16(float x0, float x1) {
    union { __hip_bfloat162 h; unsigned int u; } cv;
    cv.h = __float22bfloat162_rn(make_float2(x0, x1));
    return cv.u;
}
__device__ __forceinline__ void async16(const void* g, void* l) {
    __builtin_amdgcn_global_load_lds((const __attribute__((address_space(1))) void*)g,
                                     (__attribute__((address_space(3))) void*)l, 16, 0, 0);
}

// ---------- wave helpers (wave = 64) ----------
__device__ __forceinline__ float wsum(float v) {
#pragma unroll
    for (int o = 32; o > 0; o >>= 1) v += __shfl_xor(v, o);
    return v;
}
__device__ __forceinline__ float wmax(float v) {
#pragma unroll
    for (int o = 32; o > 0; o >>= 1) v = fmaxf(v, __shfl_xor(v, o));
    return v;
}

// ---------- weight prep: conv_w fp32 -> hi/lo bf16, PERMUTED [k/8][e][8] ----------
__global__ __launch_bounds__(256) void split_cw_k(const float* __restrict__ cw,
    unsigned short* __restrict__ cwh, unsigned short* __restrict__ cwl)
{
    int i = blockIdx.x * 256 + threadIdx.x;     // 288 kg * 256 e = 73728
    int e = i & 255, kg = i >> 8;               // kg 0..287
    if (kg >= 288) return;
    const float4* sp = (const float4*)(cw + (size_t)e * KCV + kg * 8);
    float4 x0 = sp[0], x1 = sp[1];
    float av[8] = {x0.x, x0.y, x0.z, x0.w, x1.x, x1.y, x1.z, x1.w};
    short8 hh, ll;
#pragma unroll
    for (int j = 0; j < 8; ++j) {
        unsigned short h = f2bf(av[j]);
        hh[j] = (short)h;
        ll[j] = (short)f2bf(av[j] - bf2f(h));
    }
    size_t off = (size_t)kg * 2048 + e * 8;
    *(short8*)&cwh[off] = hh;
    *(short8*)&cwl[off] = ll;
}

// ---------- weight prep: 6 fp32 matrices -> one bf16 pool ----------
// offsets: wk 0, wv 65536, in_proj 131072 (3E*E), out_proj 327680, dense 393216, bproj 458752
__global__ __launch_bounds__(256) void cast_w_k(
    const float* __restrict__ s0, const float* __restrict__ s1, const float* __restrict__ s2,
    const float* __restrict__ s3, const float* __restrict__ s4, const float* __restrict__ s5,
    unsigned short* __restrict__ dst)
{
    int i = blockIdx.x * 256 + threadIdx.x;
    if (i >= 524288) return;
    float v;
    if      (i <  65536) v = s0[i];
    else if (i < 131072) v = s1[i - 65536];
    else if (i < 327680) v = s2[i - 131072];
    else if (i < 393216) v = s3[i - 327680];
    else if (i < 458752) v = s4[i - 393216];
    else                 v = s5[i - 458752];
    dst[i] = f2bf(v);
}

// ---------- conv as implicit GEMM on MFMA, fp32 accuracy via hi/lo bf16 split ----------
// v4: 64m x 64e, flat grid 784 with XCD-grouped swizzle (4 e-blocks sharing an
// A-panel land consecutively on one XCD -> L2 hits). BK=64: 36 steps, 24 MFMA per
// wave per barrier (halved barrier count). A in registers (frag layout), prefetch
// depth 1 step; B hi/lo double-buffered in 32KB LDS via global_load_lds.
__global__ __launch_bounds__(256) void conv_mfma_k(
    const float* __restrict__ video, const unsigned short* __restrict__ cwh,
    const unsigned short* __restrict__ cwl, const float* __restrict__ cbias,
    float* __restrict__ tokmean4, unsigned short* __restrict__ outB)
{
    __shared__ __align__(16) unsigned short Bh[8192], Bl[8192];  // 2 bufs x [kg8][e64][8]
    const int t    = threadIdx.x;
    const int lane = t & 63;
    const int w    = t >> 6;
    const int l15  = lane & 15, lq = lane >> 4;
    // XCD-grouped swizzle: 784 = 8 xcd * 98; within an XCD, consecutive slots are
    // the 4 e-blocks of one m-block (shared A-panel -> L2 hits).
    const int v_  = blockIdx.x;
    const int s_  = (v_ & 7) * 98 + (v_ >> 3);
    const int mb  = s_ >> 2, eb = s_ & 3;
    const int m0  = mb * 64, e0 = eb * 64;

    // This lane's A row (== its MFMA A-frag row): m = m0 + w*16 + l15
    const int m = m0 + w * 16 + l15;
    const int b = m / NTOK, n = m % NTOK;
    const int d = n / 196, hw = n % 196;
    const int h = hw / 14, ww = hw % 14;
    const float* vb = video + (size_t)(b * 3) * (32 * 50176) + (h * 16) * 224 + ww * 16;
    const int dbase = 2 * d - 1;

    f32x4 acc[4] = {};
    float4 a0, a1, a2, a3, b0, b1, b2, b3;   // cur / next step (16 floats each)

    // stage B(step s, BK=64) into buffer `buf`: wave w stages kg_local = w, w+4
    // for hi and lo; per-lane global src (coalesced 1KB), wave-uniform LDS dest.
#define STAGE_B(s, buf)                                                              \
    {                                                                                \
        _Pragma("unroll")                                                            \
        for (int r_ = 0; r_ < 2; ++r_) {                                             \
            const int kgl = w + r_ * 4;                                              \
            const size_t gsrc = (size_t)((s) * 8 + kgl) * 2048 + (e0 + lane) * 8;    \
            async16(cwh + gsrc, &Bh[(buf) * 4096 + kgl * 512]);                      \
            async16(cwl + gsrc, &Bl[(buf) * 4096 + kgl * 512]);                      \
        }                                                                            \
    }
#define LOAD_A32(k0v, x0, x1)                                                        \
    {                                                                                \
        const int k0  = (k0v) + lq * 8;                                              \
        const int c   = k0 / 768;                                                    \
        const int rem = k0 - c * 768;                                                \
        const int kd  = rem >> 8;                                                    \
        const int r2  = rem & 255;                                                   \
        const int id  = dbase + kd;                                                  \
        x0 = make_float4(0.f, 0.f, 0.f, 0.f); x1 = x0;                               \
        if (id >= 0) {                                                               \
            const float* p = vb + (size_t)c * (32 * 50176) + id * 50176 +            \
                             (r2 >> 4) * 224 + (r2 & 15);                            \
            x0 = *(const float4*)p;                                                  \
            x1 = *(const float4*)(p + 4);                                            \
        }                                                                            \
    }
    // convert 8 fp32 (two float4) -> hi/lo bf16 frags
#define CVT_AB(y0, y1, fah, fal)                                                     \
    short8 fah, fal;                                                                 \
    {                                                                                \
        float av[8] = {y0.x, y0.y, y0.z, y0.w, y1.x, y1.y, y1.z, y1.w};              \
        unsigned int ph[4], pl[4];                                                   \
        _Pragma("unroll")                                                            \
        for (int j = 0; j < 4; ++j) {                                                \
            float u0 = av[2 * j], u1 = av[2 * j + 1];                                \
            unsigned int hu = cvt_pk_bf16(u0, u1);                                   \
            float r0 = u0 - __uint_as_float(hu << 16);                               \
            float r1 = u1 - __uint_as_float(hu & 0xffff0000u);                       \
            ph[j] = hu;                                                              \
            pl[j] = cvt_pk_bf16(r0, r1);                                             \
        }                                                                            \
        int4 phv = make_int4(ph[0], ph[1], ph[2], ph[3]);                            \
        int4 plv = make_int4(pl[0], pl[1], pl[2], pl[3]);                            \
        fah = *(short8*)&phv;                                                        \
        fal = *(short8*)&plv;                                                        \
    }

    // prologue: stage step 0; load A(0)
    STAGE_B(0, 0);
    LOAD_A32(0, a0, a1);
    LOAD_A32(32, a2, a3);
    __syncthreads();

    for (int s = 0; s < 36; ++s) {
        const int cbuf = s & 1;
        if (s + 1 < 36) {
            STAGE_B(s + 1, cbuf ^ 1);
            LOAD_A32((s + 1) * 64,      b0, b1);
            LOAD_A32((s + 1) * 64 + 32, b2, b3);
        }
        // substep 0 (k 0..31 of this 64-chunk)
        {
            CVT_AB(a0, a1, fah, fal);
            const int rb = cbuf * 4096 + lq * 512 + l15 * 8;
#pragma unroll
            for (int ct = 0; ct < 4; ++ct) {
                short8 fbh = *(const short8*)&Bh[rb + ct * 128];
                short8 fbl = *(const short8*)&Bl[rb + ct * 128];
                acc[ct] = __builtin_amdgcn_mfma_f32_16x16x32_bf16(fah, fbh, acc[ct], 0, 0, 0);
                acc[ct] = __builtin_amdgcn_mfma_f32_16x16x32_bf16(fah, fbl, acc[ct], 0, 0, 0);
                acc[ct] = __builtin_amdgcn_mfma_f32_16x16x32_bf16(fal, fbh, acc[ct], 0, 0, 0);
            }
        }
        // substep 1 (k 32..63)
        {
            CVT_AB(a2, a3, fah, fal);
            const int rb = cbuf * 4096 + (4 + lq) * 512 + l15 * 8;
#pragma unroll
            for (int ct = 0; ct < 4; ++ct) {
                short8 fbh = *(const short8*)&Bh[rb + ct * 128];
                short8 fbl = *(const short8*)&Bl[rb + ct * 128];
                acc[ct] = __builtin_amdgcn_mfma_f32_16x16x32_bf16(fah, fbh, acc[ct], 0, 0, 0);
                acc[ct] = __builtin_amdgcn_mfma_f32_16x16x32_bf16(fah, fbl, acc[ct], 0, 0, 0);
                acc[ct] = __builtin_amdgcn_mfma_f32_16x16x32_bf16(fal, fbh, acc[ct], 0, 0, 0);
            }
        }
        __syncthreads();   // drains vmcnt (next-step prefetch) + lgkm; flips buffer
        a0 = b0; a1 = b1; a2 = b2; a3 = b3;
    }
#undef STAGE_B
#undef LOAD_A32
#undef CVT_AB

    // C/D: col(e) = lane&15, row(m) = (lane>>4)*4 + reg  [m89]
    const int rbase = m0 + w * 16 + lq * 4;
    float rsum[4] = {0.f, 0.f, 0.f, 0.f};
#pragma unroll
    for (int ct = 0; ct < 4; ++ct) {
        int e = e0 + ct * 16 + l15;
        float bias = cbias[e];
#pragma unroll
        for (int r = 0; r < 4; ++r) {
            float vv = fmaxf(acc[ct][r] + bias, 0.f);
            outB[(size_t)(rbase + r) * 256 + e] = f2bf(vv);
            rsum[r] += vv;
        }
    }
    if (m0 < NTOK) {   // batch-0 block: emit 64-e partial sum for the byte path
#pragma unroll
        for (int r = 0; r < 4; ++r) {
            float sv = rsum[r];
            sv += __shfl_xor(sv, 1); sv += __shfl_xor(sv, 2);
            sv += __shfl_xor(sv, 4); sv += __shfl_xor(sv, 8);
            if (l15 == 0) tokmean4[(size_t)eb * NTOK + rbase + r] = sv;
        }
    }
}

// ---------- bf16 MFMA GEMM, K=256, 2-phase staging, XCD swizzle (784 blocks) ----------
// C[m,e] = sum_k A[m,k]*W[e,k] + bias[e] (+addvec[e]) (mask m%NTOK >= *Sptr -> 0)
__global__ __launch_bounds__(256) void gemm_single_k(
    const unsigned short* __restrict__ A, const unsigned short* __restrict__ W,
    const float* __restrict__ bias, const float* __restrict__ addvec,
    const int* __restrict__ Sptr, float* __restrict__ outF, unsigned short* __restrict__ outB)
{
    __shared__ __align__(16) unsigned short As[8192], Bs[8192];   // 16 KB + 16 KB
    const int t = threadIdx.x, lane = t & 63, w = t >> 6;
    const int v_ = blockIdx.x;
    const int s_ = (v_ & 7) * 98 + (v_ >> 3);          // 784 = 8*98
    const int m0 = (s_ >> 2) * 64, e0 = (s_ & 3) * 64;
    const int l15 = lane & 15, lq = lane >> 4;
    const unsigned short* ga = A + (size_t)(m0 + lane) * 256;
    const unsigned short* gb = W + (size_t)(e0 + lane) * 256;
    // phase 1: kg 0..15
#pragma unroll
    for (int kg = w; kg < 16; kg += 4) {
        async16(ga + kg * 8, &As[kg * 512]);
        async16(gb + kg * 8, &Bs[kg * 512]);
    }
    f32x4 acc[4] = {};
    __syncthreads();
    // phase 2 loads fly under phase-1 compute (LDS reused via ping... disjoint halves)
    // NOTE: As/Bs sized 8192 shorts = 16 kg; phase 2 overwrites nothing until sync2?
    // -> stage phase 2 into the SAME buffers' upper half is impossible (16 kg only).
    // Instead we use full 32-kg buffers: see sizes below.
    ;
    // (unreachable comment retained for clarity)
    int S = Sptr ? *Sptr : 0x7fffffff;
#pragma unroll
    for (int s = 0; s < 4; ++s) {
        int kg = s * 4 + lq;
        short8 a = *(const short8*)&As[(kg & 15) * 512 + (w * 16 + l15) * 8];
        short8 a_dummy = a; (void)a_dummy;
        // placeholder - real loop below
        break;
    }
    // ---- real implementation with full 32-kg staging in two phases ----
    // (the arrays above are 16 kg; we re-stage second half after first compute)
    // compute kg 0..15
#pragma unroll
    for (int s = 0; s < 4; ++s) {
        int kg = s * 4 + lq;
        short8 a = *(const short8*)&As[kg * 512 + (w * 16 + l15) * 8];
#pragma unroll
        for (int ct = 0; ct < 4; ++ct) {
            short8 bb = *(const short8*)&Bs[kg * 512 + (ct * 16 + l15) * 8];
            acc[ct] = __builtin_amdgcn_mfma_f32_16x16x32_bf16(a, bb, acc[ct], 0, 0, 0);
        }
    }
    __syncthreads();           // reads of half-1 done; safe to overwrite
    // phase 2: kg 16..31 into same buffers
#pragma unroll
    for (int kg = w; kg < 16; kg += 4) {
        async16(ga + (16 + kg) * 8, &As[kg * 512]);
        async16(gb + (16 + kg) * 8, &Bs[kg * 512]);
    }
    __syncthreads();
#pragma unroll
    for (int s = 0; s < 4; ++s) {
        int kg = s * 4 + lq;
        short8 a = *(const short8*)&As[kg * 512 + (w * 16 + l15) * 8];
#pragma unroll
        for (int ct = 0; ct < 4; ++ct) {
            short8 bb = *(const short8*)&Bs[kg * 512 + (ct * 16 + l15) * 8];
            acc[ct] = __builtin_amdgcn_mfma_f32_16x16x32_bf16(a, bb, acc[ct], 0, 0, 0);
        }
    }
    int rbase = m0 + w * 16 + lq * 4;
#pragma unroll
    for (int ct = 0; ct < 4; ++ct) {
        int e = e0 + ct * 16 + l15;
        float bv = bias[e] + (addvec ? addvec[e] : 0.f);
#pragma unroll
        for (int r = 0; r < 4; ++r) {
            int mm = rbase + r;
            float vv = acc[ct][r] + bv;
            if ((mm % NTOK) >= S) vv = 0.f;
            size_t off = (size_t)mm * 256 + e;
            if (outF) outF[off] = vv;
            if (outB) outB[off] = f2bf(vv);
        }
    }
}

// ---------- fused dual GEMM: 1568 blocks; y-half selects A/bias/out; W rows contiguous ----------
__global__ __launch_bounds__(256) void gemm_dual_k(
    const unsigned short* __restrict__ A0, const unsigned short* __restrict__ A1,
    const unsigned short* __restrict__ W,
    const float* __restrict__ bias0, const float* __restrict__ bias1,
    unsigned short* __restrict__ outB0, unsigned short* __restrict__ outB1)
{
    __shared__ __align__(16) unsigned short As[8192], Bs[8192];
    const int t = threadIdx.x, lane = t & 63, w = t >> 6;
    const int v_ = blockIdx.x;
    const int s_ = (v_ & 7) * 196 + (v_ >> 3);         // 1568 = 8*196
    const int mb = s_ >> 3, ebg = s_ & 7;              // ebg 0..7 over 512 W rows
    const int half = ebg >> 2;
    const unsigned short* A = half ? A1 : A0;
    const float* bias = half ? bias1 : bias0;
    unsigned short* outB = half ? outB1 : outB0;
    const int m0 = mb * 64, eg0 = ebg * 64, el0 = (ebg & 3) * 64;
    const int l15 = lane & 15, lq = lane >> 4;
    const unsigned short* ga = A + (size_t)(m0 + lane) * 256;
    const unsigned short* gb = W + (size_t)(eg0 + lane) * 256;
#pragma unroll
    for (int kg = w; kg < 16; kg += 4) {
        async16(ga + kg * 8, &As[kg * 512]);
        async16(gb + kg * 8, &Bs[kg * 512]);
    }
    f32x4 acc[4] = {};
    __syncthreads();
#pragma unroll
    for (int s = 0; s < 4; ++s) {
        int kg = s * 4 + lq;
        short8 a = *(const short8*)&As[kg * 512 + (w * 16 + l15) * 8];
#pragma unroll
        for (int ct = 0; ct < 4; ++ct) {
            short8 bb = *(const short8*)&Bs[kg * 512 + (ct * 16 + l15) * 8];
            acc[ct] = __builtin_amdgcn_mfma_f32_16x16x32_bf16(a, bb, acc[ct], 0, 0, 0);
        }
    }
    __syncthreads();
#pragma unroll
    for (int kg = w; kg < 16; kg += 4) {
        async16(ga + (16 + kg) * 8, &As[kg * 512]);
        async16(gb + (16 + kg) * 8, &Bs[kg * 512]);
    }
    __syncthreads();
#pragma unroll
    for (int s = 0; s < 4; ++s) {
        int kg = s * 4 + lq;
        short8 a = *(const short8*)&As[kg * 512 + (w * 16 + l15) * 8];
#pragma unroll
        for (int ct = 0; ct < 4; ++ct) {
            short8 bb = *(const short8*)&Bs[kg * 512 + (ct * 16 + l15) * 8];
            acc[ct] = __builtin_amdgcn_mfma_f32_16x16x32_bf16(a, bb, acc[ct], 0, 0, 0);
        }
    }
    int rbase = m0 + w * 16 + lq * 4;
#pragma unroll
    for (int ct = 0; ct < 4; ++ct) {
        int e = el0 + ct * 16 + l15;
        float bv = bias[e];
#pragma unroll
        for (int r = 0; r < 4; ++r) {
            float vv = acc[ct][r] + bv;
            outB[(size_t)(rbase + r) * 256 + e] = f2bf(vv);
        }
    }
}

// ---------- tokmean4 -> byte -> entropy -> boundary (b=0 only) ----------
__global__ __launch_bounds__(256) void boundary_k(
    const float* __restrict__ tokmean4, const float* __restrict__ ent_table,
    int* __restrict__ boundary)
{
    int n    = blockIdx.x * 4 + (threadIdx.x >> 6);
    int lane = threadIdx.x & 63;
    float s0 = tokmean4[n];
    float s1 = tokmean4[NTOK + n];
    float s2 = tokmean4[2 * NTOK + n];
    float s3 = tokmean4[3 * NTOK + n];
    float mean = ((s0 + s1) + (s2 + s3)) * (1.f / 256.f);   // deterministic order
    float bf = rintf(mean * 255.f);
    bf = fminf(fmaxf(bf, 0.f), 255.f);
    int byte = (int)bf;
    const float4 lg = reinterpret_cast<const float4*>(ent_table + byte * 256)[lane];
    float mx = wmax(fmaxf(fmaxf(lg.x, lg.y), fmaxf(lg.z, lg.w)));
    float e0 = expf(lg.x - mx), e1 = expf(lg.y - mx), e2 = expf(lg.z - mx), e3 = expf(lg.w - mx);
    float z = wsum(e0 + e1 + e2 + e3);
    float iz = 1.f / z;
    float p0 = e0 * iz, p1 = e1 * iz, p2 = e2 * iz, p3 = e3 * iz;
    float ep = -(p0 * log2f(p0 + 1e-9f) + p1 * log2f(p1 + 1e-9f) +
                 p2 * log2f(p2 + 1e-9f) + p3 * log2f(p3 + 1e-9f));
    ep = wsum(ep);
    if (lane == 0) boundary[n] = (ep > THRESH) ? 1 : 0;
}

// ---------- single-block scan: boundary -> seg_start[], S ----------
__global__ __launch_bounds__(256) void scan_k(const int* __restrict__ boundary,
    int* __restrict__ seg_start, int* __restrict__ Sptr)
{
    __shared__ int sums[256];
    const int t = threadIdx.x;
    const int CH = 13;
    int base = t * CH;
    int s = 0;
    for (int i = 0; i < CH; i++) { int n = base + i; if (n < NTOK) s += boundary[n]; }
    sums[t] = s; __syncthreads();
    for (int o = 1; o < 256; o <<= 1) {
        int v = sums[t];
        int u = (t >= o) ? sums[t - o] : 0;
        __syncthreads();
        sums[t] = v + u;
        __syncthreads();
    }
    int run = (t == 0) ? 0 : sums[t - 1];
    if (t == 0) seg_start[0] = 0;
    for (int i = 0; i < CH; i++) {
        int n = base + i;
        if (n >= NTOK) break;
        int v = boundary[n];
        if (n == NTOK - 1) { Sptr[0] = run + 1; seg_start[run + 1] = NTOK; }
        if (v && (n + 1 < NTOK)) seg_start[run + 1] = n + 1;
        run += v;
    }
}

// ---------- fused dual LayerNorm: bf16 in -> bf16 out; rows [0,MT) = K, [MT,2MT) = V ----------
__global__ __launch_bounds__(256) void lnKV_k(
    const unsigned short* __restrict__ Pk, const unsigned short* __restrict__ Pv,
    const float* __restrict__ gk, const float* __restrict__ bk,
    const float* __restrict__ gv, const float* __restrict__ bv,
    unsigned short* __restrict__ Yk, unsigned short* __restrict__ Yv)
{
    int row  = blockIdx.x * 4 + (threadIdx.x >> 6);   // 0..2*MT-1
    int lane = threadIdx.x & 63;
    int half = row >= MT;
    int r    = half ? row - MT : row;
    const unsigned short* X = half ? Pv : Pk;
    const float* g = half ? gv : gk;
    const float* b = half ? bv : bk;
    unsigned short* Y = half ? Yv : Yk;
    ushort4 xr = reinterpret_cast<const ushort4*>(X + (size_t)r * 256)[lane];
    float x0 = bf2f(xr.x), x1 = bf2f(xr.y), x2 = bf2f(xr.z), x3 = bf2f(xr.w);
    float m = wsum(x0 + x1 + x2 + x3) * (1.f / 256.f);
    float d0 = x0 - m, d1 = x1 - m, d2 = x2 - m, d3 = x3 - m;
    float var = wsum(d0 * d0 + d1 * d1 + d2 * d2 + d3 * d3) * (1.f / 256.f);
    float inv = 1.f / sqrtf(var + LN_EPS);
    float4 g4 = reinterpret_cast<const float4*>(g)[lane];
    float4 b4 = reinterpret_cast<const float4*>(b)[lane];
    ushort4 y;
    y.x = f2bf(d0 * inv * g4.x + b4.x);
    y.y = f2bf(d1 * inv * g4.y + b4.y);
    y.z = f2bf(d2 * inv * g4.z + b4.z);
    y.w = f2bf(d3 * inv * g4.w + b4.w);
    reinterpret_cast<ushort4*>(Y + (size_t)r * 256)[lane] = y;
}

// ---------- query path: qp[256], batch-invariant, one block, fp32 ----------
__global__ __launch_bounds__(256) void query_k(
    const float* __restrict__ gq, const float* __restrict__ wq_w, const float* __restrict__ wq_b,
    const float* __restrict__ lnq_g, const float* __restrict__ lnq_b,
    const float* __restrict__ inW, const float* __restrict__ inB, float* __restrict__ qp)
{
    __shared__ float sh[256];
    __shared__ float red[256];
    const int t = threadIdx.x;
    float acc = wq_b[t];
    for (int j = 0; j < 256; j++) acc += gq[j] * wq_w[t * 256 + j];
    red[t] = acc; __syncthreads();
    for (int o = 128; o > 0; o >>= 1) { if (t < o) red[t] += red[t + o]; __syncthreads(); }
    float m = red[0] * (1.f / 256.f);
    __syncthreads();
    float d = acc - m;
    red[t] = d * d; __syncthreads();
    for (int o = 128; o > 0; o >>= 1) { if (t < o) red[t] += red[t + o]; __syncthreads(); }
    float inv = 1.f / sqrtf(red[0] * (1.f / 256.f) + LN_EPS);
    sh[t] = d * inv * lnq_g[t] + lnq_b[t];
    __syncthreads();
    float a2 = inB[t];
    for (int j = 0; j < 256; j++) a2 += sh[j] * inW[t * 256 + j];
    qp[t] = a2 * 0.125f;
}

// ---------- scores[n,b,h] = dot(qp[h], kp[b,n,h]); kp bf16; one wave per (b,n) ----------
__global__ __launch_bounds__(256) void scores_k(const unsigned short* __restrict__ kp,
    const float* __restrict__ qp, float* __restrict__ sc)
{
    int idx  = blockIdx.x * 4 + (threadIdx.x >> 6);   // b*NTOK + n
    int lane = threadIdx.x & 63;
    ushort4 k4 = reinterpret_cast<const ushort4*>(kp + (size_t)idx * 256)[lane];
    float4 q4 = reinterpret_cast<const float4*>(qp)[lane];
    float p = bf2f(k4.x) * q4.x + bf2f(k4.y) * q4.y + bf2f(k4.z) * q4.z + bf2f(k4.w) * q4.w;
    p += __shfl_xor(p, 1); p += __shfl_xor(p, 2);
    p += __shfl_xor(p, 4); p += __shfl_xor(p, 8);
    if ((lane & 15) == 0) {
        int b = idx / NTOK, n = idx % NTOK;
        int h = lane >> 4;
        sc[(b * 4 + h) * NTOK + n] = p;
    }
}

// ---------- segment softmax-attention; vp bf16 in, attn bf16 out ----------
__global__ __launch_bounds__(256) void attn_bf_k(const float* __restrict__ sc,
    const unsigned short* __restrict__ vp, const int* __restrict__ seg_start,
    const int* __restrict__ Sptr, unsigned short* __restrict__ attn)
{
    int s    = blockIdx.x;
    int b    = threadIdx.x >> 6;
    int lane = threadIdx.x & 63;
    unsigned short* orow = attn + ((size_t)b * NTOK + s) * 256;
    int S = *Sptr;
    if (s >= S) {
#pragma unroll
        for (int h = 0; h < 4; h++) orow[h * 64 + lane] = 0;
        return;
    }
    int st = seg_start[s], en = seg_start[s + 1];
    for (int h = 0; h < 4; h++) {
        const float* scr = sc + (b * 4 + h) * NTOK;
        float m = -1e30f;
        for (int n = st; n < en; n++) m = fmaxf(m, scr[n]);
        float den = 0.f, acc = 0.f;
        for (int n = st; n < en; n++) {
            float wgt = expf(scr[n] - m);
            den += wgt;
            acc += wgt * bf2f(vp[((size_t)b * NTOK + n) * 256 + h * 64 + lane]);
        }
        orow[h * 64 + lane] = f2bf(acc / den);
    }
}

extern "C" void kernel_launch(void* const* d_in, const int* in_sizes, int n_in,
                              void* d_out, int out_size, void* d_ws, size_t ws_size,
                              hipStream_t stream)
{
    const float* video      = (const float*)d_in[0];
    const float* conv_w     = (const float*)d_in[1];
    const float* conv_b     = (const float*)d_in[2];
    const float* wq_w       = (const float*)d_in[3];
    const float* wq_b       = (const float*)d_in[4];
    const float* wk_w       = (const float*)d_in[5];
    const float* wk_b       = (const float*)d_in[6];
    const float* wv_w       = (const float*)d_in[7];
    const float* wv_b       = (const float*)d_in[8];
    const float* lnq_g      = (const float*)d_in[9];
    const float* lnq_b      = (const float*)d_in[10];
    const float* lnk_g      = (const float*)d_in[11];
    const float* lnk_b      = (const float*)d_in[12];
    const float* lnv_g      = (const float*)d_in[13];
    const float* lnv_b      = (const float*)d_in[14];
    const float* in_proj_w  = (const float*)d_in[15];
    const float* in_proj_b  = (const float*)d_in[16];
    const float* out_proj_w = (const float*)d_in[17];
    const float* out_proj_b = (const float*)d_in[18];
    const float* dense_w    = (const float*)d_in[19];
    const float* dense_b    = (const float*)d_in[20];
    const float* bproj_w    = (const float*)d_in[21];
    const float* bproj_b    = (const float*)d_in[22];
    const float* group_q    = (const float*)d_in[23];
    const float* ent_table  = (const float*)d_in[24];
    float* out = (float*)d_out;

    // ---- workspace layout (~48.7 MB) ----
    float* tokmean4 = (float*)d_ws;                      // 4*NTOK floats (+pad to 16384)
    unsigned short* Pk  = (unsigned short*)(tokmean4 + 16384);   // pre-LN K (bf16)
    unsigned short* Pv  = Pk  + (size_t)MT * 256;        // pre-LN V (bf16)
    unsigned short* B1  = Pv  + (size_t)MT * 256;        // tokens / attn-out
    unsigned short* B2k = B1  + (size_t)MT * 256;        // kln / o1
    unsigned short* B2v = B2k + (size_t)MT * 256;        // vln / o2
    unsigned short* B3k = B2v + (size_t)MT * 256;        // kp
    unsigned short* B3v = B3k + (size_t)MT * 256;        // vp
    unsigned short* cwh = B3v + (size_t)MT * 256;        // conv weights hi (permuted)
    unsigned short* cwl = cwh + 256 * KCV;               // conv weights lo (permuted)
    unsigned short* wpool = cwl + 256 * KCV;             // 524288 bf16 weights
    float* sc = (float*)(wpool + 524288);                // scores [B*NH][NTOK]
    float* qp = sc + 16 * NTOK;
    int* boundary  = (int*)(qp + 256);
    int* seg_start = boundary + NTOK;
    int* Sp        = seg_start + (NTOK + 1);

    const unsigned short* inpb   = wpool + 131072;       // 3E x E
    const unsigned short* outpb  = wpool + 327680;
    const unsigned short* denseb = wpool + 393216;
    const unsigned short* bprojb = wpool + 458752;

    dim3 blk(256);
    split_cw_k<<<dim3(288), blk, 0, stream>>>(conv_w, cwh, cwl);
    cast_w_k<<<dim3(2048), blk, 0, stream>>>(wk_w, wv_w, in_proj_w, out_proj_w,
                                             dense_w, bproj_w, wpool);
    conv_mfma_k<<<dim3(784), blk, 0, stream>>>(video, cwh, cwl, conv_b, tokmean4, B1);
    boundary_k<<<dim3(NTOK / 4), blk, 0, stream>>>(tokmean4, ent_table, boundary);
    scan_k<<<dim3(1), blk, 0, stream>>>(boundary, seg_start, Sp);
    query_k<<<dim3(1), blk, 0, stream>>>(group_q, wq_w, wq_b, lnq_g, lnq_b,
                                         in_proj_w, in_proj_b, qp);
    // fused K+V pre-LN GEMM: W rows 0..255 = wk, 256..511 = wv (contiguous in pool)
    gemm_dual_k<<<dim3(1568), blk, 0, stream>>>(B1, B1, wpool, wk_b, wv_b, Pk, Pv);
    // fused K+V LayerNorm
    lnKV_k<<<dim3(2 * MT / 4), blk, 0, stream>>>(Pk, Pv, lnk_g, lnk_b, lnv_g, lnv_b,
                                                 B2k, B2v);
    // fused kp+vp projection: W rows 256..767 of in_proj (Wki||Wvi contiguous)
    gemm_dual_k<<<dim3(1568), blk, 0, stream>>>(B2k, B2v, inpb + 65536,
                                                in_proj_b + 256, in_proj_b + 512,
                                                B3k, B3v);
    scores_k<<<dim3(MT / 4), blk, 0, stream>>>(B3k, qp, sc);
    attn_bf_k<<<dim3(NTOK), blk, 0, stream>>>(sc, B3v, seg_start, Sp, B1);
    // tail projections
    gemm_single_k<<<dim3(784), blk, 0, stream>>>(B1, outpb, out_proj_b,
                                                 nullptr, nullptr, nullptr, B2k);
    gemm_single_k<<<dim3(784), blk, 0, stream>>>(B2k, denseb, dense_b,
                                                 group_q, nullptr, nullptr, B2v);
    gemm_single_k<<<dim3(784), blk, 0, stream>>>(B2v, bprojb, bproj_b,
                                                 nullptr, Sp, out, nullptr);
}

// Round 4
// 329.338 us; speedup vs baseline: 1.2722x; 1.0755x over previous
//
#include <hip/hip_runtime.h>
#include <hip/hip_bf16.h>
#include <math.h>

#define NTOK 3136           // 16*14*14 tokens
#define MT 12544            // 4 * NTOK
#define KCV 2304            // 3*3*16*16
#define THRESH 1.5f
#define LN_EPS 1e-5f

typedef short short8 __attribute__((ext_vector_type(8)));
typedef float f32x4 __attribute__((ext_vector_type(4)));

// ---------- bf16 helpers ----------
__device__ __forceinline__ unsigned short f2bf(float f) {   // manual RTNE (cold paths)
    unsigned int u = __float_as_uint(f);
    u += 0x7fffu + ((u >> 16) & 1u);
    return (unsigned short)(u >> 16);
}
__device__ __forceinline__ float bf2f(unsigned short h) {
    return __uint_as_float(((unsigned int)h) << 16);
}
// HW packed cvt (v_cvt_pk_bf16_f32, RTNE): low16 = bf(x0), high16 = bf(x1)
__device__ __forceinline__ unsigned int cvt_pk_bf16(float x0, float x1) {
    union { __hip_bfloat162 h; unsigned int u; } cv;
    cv.h = __float22bfloat162_rn(make_float2(x0, x1));
    return cv.u;
}
__device__ __forceinline__ void async16(const void* g, void* l) {
    __builtin_amdgcn_global_load_lds((const __attribute__((address_space(1))) void*)g,
                                     (__attribute__((address_space(3))) void*)l, 16, 0, 0);
}

// ---------- wave helpers (wave = 64) ----------
__device__ __forceinline__ float wsum(float v) {
#pragma unroll
    for (int o = 32; o > 0; o >>= 1) v += __shfl_xor(v, o);
    return v;
}
__device__ __forceinline__ float wmax(float v) {
#pragma unroll
    for (int o = 32; o > 0; o >>= 1) v = fmaxf(v, __shfl_xor(v, o));
    return v;
}

// ---------- prep mega-kernel: split_cw (288) + cast_w (2048) + query (1) ----------
// conv weights -> hi/lo bf16 PERMUTED [k/8][e][8]; 6 matrices -> bf16 pool; qp[256].
__global__ __launch_bounds__(256) void prep_k(
    const float* __restrict__ cw, unsigned short* __restrict__ cwh,
    unsigned short* __restrict__ cwl,
    const float* __restrict__ s0, const float* __restrict__ s1, const float* __restrict__ s2,
    const float* __restrict__ s3, const float* __restrict__ s4, const float* __restrict__ s5,
    unsigned short* __restrict__ dst,
    const float* __restrict__ gq, const float* __restrict__ wq_w,
    const float* __restrict__ wq_b, const float* __restrict__ lnq_g,
    const float* __restrict__ lnq_b, const float* __restrict__ inW,
    const float* __restrict__ inB, float* __restrict__ qp)
{
    const int blk = blockIdx.x;
    if (blk < 288) {
        // split_cw: conv_w fp32 -> hi/lo bf16, permuted [kg][e][8]
        int i = blk * 256 + threadIdx.x;         // 288 kg * 256 e
        int e = i & 255, kg = i >> 8;
        const float4* sp = (const float4*)(cw + (size_t)e * KCV + kg * 8);
        float4 x0 = sp[0], x1 = sp[1];
        float av[8] = {x0.x, x0.y, x0.z, x0.w, x1.x, x1.y, x1.z, x1.w};
        short8 hh, ll;
#pragma unroll
        for (int j = 0; j < 8; ++j) {
            unsigned short h = f2bf(av[j]);
            hh[j] = (short)h;
            ll[j] = (short)f2bf(av[j] - bf2f(h));
        }
        size_t off = (size_t)kg * 2048 + e * 8;
        *(short8*)&cwh[off] = hh;
        *(short8*)&cwl[off] = ll;
    } else if (blk < 2336) {
        // cast_w: offsets wk 0, wv 65536, in_proj 131072, out_proj 327680,
        //         dense 393216, bproj 458752
        int i = (blk - 288) * 256 + threadIdx.x;
        if (i >= 524288) return;
        float v;
        if      (i <  65536) v = s0[i];
        else if (i < 131072) v = s1[i - 65536];
        else if (i < 327680) v = s2[i - 131072];
        else if (i < 393216) v = s3[i - 327680];
        else if (i < 458752) v = s4[i - 393216];
        else                 v = s5[i - 458752];
        dst[i] = f2bf(v);
    } else {
        // query path: qp[256], batch-invariant, fp32
        __shared__ float sh[256];
        __shared__ float red[256];
        const int t = threadIdx.x;
        float acc = wq_b[t];
        for (int j = 0; j < 256; j++) acc += gq[j] * wq_w[t * 256 + j];
        red[t] = acc; __syncthreads();
        for (int o = 128; o > 0; o >>= 1) { if (t < o) red[t] += red[t + o]; __syncthreads(); }
        float m = red[0] * (1.f / 256.f);
        __syncthreads();
        float d = acc - m;
        red[t] = d * d; __syncthreads();
        for (int o = 128; o > 0; o >>= 1) { if (t < o) red[t] += red[t + o]; __syncthreads(); }
        float inv = 1.f / sqrtf(red[0] * (1.f / 256.f) + LN_EPS);
        sh[t] = d * inv * lnq_g[t] + lnq_b[t];
        __syncthreads();
        float a2 = inB[t];
        for (int j = 0; j < 256; j++) a2 += sh[j] * inW[t * 256 + j];
        qp[t] = a2 * 0.125f;
    }
}

// ---------- conv as implicit GEMM on MFMA, fp32 accuracy via hi/lo bf16 split ----------
// v5: 64m x 64e, XCD-grouped swizzle, BK=64 (36 steps). A in registers (frag layout),
// prefetch depth 1. B staged via REGISTERS + ds_write (T14 async-STAGE): the barrier
// drains lgkmcnt only, so the A/B global loads issued this step stay in flight across
// it (vmcnt waited only at use). This removes the vmcnt(0)-at-barrier stall that
// capped v4 at 21% MfmaUtil.
__global__ __launch_bounds__(256) void conv_mfma_k(
    const float* __restrict__ video, const unsigned short* __restrict__ cwh,
    const unsigned short* __restrict__ cwl, const float* __restrict__ cbias,
    float* __restrict__ tokmean4, unsigned short* __restrict__ outB)
{
    __shared__ __align__(16) unsigned short Bh[8192], Bl[8192];  // 2 bufs x [kg8][e64][8]
    const int t    = threadIdx.x;
    const int lane = t & 63;
    const int w    = t >> 6;
    const int l15  = lane & 15, lq = lane >> 4;
    // XCD-grouped swizzle: 784 = 8 xcd * 98; consecutive slots on one XCD are the
    // 4 e-blocks of one m-block (shared A-panel -> L2 hits).
    const int v_  = blockIdx.x;
    const int s_  = (v_ & 7) * 98 + (v_ >> 3);
    const int mb  = s_ >> 2, eb = s_ & 3;
    const int m0  = mb * 64, e0 = eb * 64;

    // This lane's A row (== its MFMA A-frag row): m = m0 + w*16 + l15
    const int m = m0 + w * 16 + l15;
    const int b = m / NTOK, n = m % NTOK;
    const int d = n / 196, hw = n % 196;
    const int h = hw / 14, ww = hw % 14;
    const float* vb = video + (size_t)(b * 3) * (32 * 50176) + (h * 16) * 224 + ww * 16;
    const int dbase = 2 * d - 1;

    f32x4 acc[4] = {};
    float4 a0, a1, a2, a3, b0, b1, b2, b3;   // A cur / next (16 floats each)
    short8 rh0, rh1, rl0, rl1;               // B staging registers (kg = w, w+4)

    // B(step s): wave w loads kg chunks w and w+4 (hi+lo) to registers.
#define BLOAD(s)                                                                     \
    {                                                                                \
        const size_t g0 = (size_t)((s) * 8 + w) * 2048 + (e0 + lane) * 8;            \
        const size_t g1 = g0 + 4 * 2048;                                             \
        rh0 = *(const short8*)(cwh + g0);                                            \
        rh1 = *(const short8*)(cwh + g1);                                            \
        rl0 = *(const short8*)(cwl + g0);                                            \
        rl1 = *(const short8*)(cwl + g1);                                            \
    }
    // write staged B regs into LDS buffer `buf` (waits vmcnt for rh*/rl* only)
#define BSTORE(buf)                                                                  \
    {                                                                                \
        const int o = (buf) * 4096 + w * 512 + lane * 8;                             \
        *(short8*)&Bh[o]        = rh0;                                               \
        *(short8*)&Bh[o + 2048] = rh1;                                               \
        *(short8*)&Bl[o]        = rl0;                                               \
        *(short8*)&Bl[o + 2048] = rl1;                                               \
    }
#define LOAD_A32(k0v, x0, x1)                                                        \
    {                                                                                \
        const int k0  = (k0v) + lq * 8;                                              \
        const int c   = k0 / 768;                                                    \
        const int rem = k0 - c * 768;                                                \
        const int kd  = rem >> 8;                                                    \
        const int r2  = rem & 255;                                                   \
        const int id  = dbase + kd;                                                  \
        x0 = make_float4(0.f, 0.f, 0.f, 0.f); x1 = x0;                               \
        if (id >= 0) {                                                               \
            const float* p = vb + (size_t)c * (32 * 50176) + id * 50176 +            \
                             (r2 >> 4) * 224 + (r2 & 15);                            \
            x0 = *(const float4*)p;                                                  \
            x1 = *(const float4*)(p + 4);                                            \
        }                                                                            \
    }
#define CVT_AB(y0, y1, fah, fal)                                                     \
    short8 fah, fal;                                                                 \
    {                                                                                \
        float av[8] = {y0.x, y0.y, y0.z, y0.w, y1.x, y1.y, y1.z, y1.w};              \
        unsigned int ph[4], pl[4];                                                   \
        _Pragma("unroll")                                                            \
        for (int j = 0; j < 4; ++j) {                                                \
            float u0 = av[2 * j], u1 = av[2 * j + 1];                                \
            unsigned int hu = cvt_pk_bf16(u0, u1);                                   \
            float r0 = u0 - __uint_as_float(hu << 16);                               \
            float r1 = u1 - __uint_as_float(hu & 0xffff0000u);                       \
            ph[j] = hu;                                                              \
            pl[j] = cvt_pk_bf16(r0, r1);                                             \
        }                                                                            \
        int4 phv = make_int4(ph[0], ph[1], ph[2], ph[3]);                            \
        int4 plv = make_int4(pl[0], pl[1], pl[2], pl[3]);                            \
        fah = *(short8*)&phv;                                                        \
        fal = *(short8*)&plv;                                                        \
    }

    // prologue: stage step 0 (pays B latency once); load A(0)
    BLOAD(0);
    LOAD_A32(0, a0, a1);
    LOAD_A32(32, a2, a3);
    BSTORE(0);
    __syncthreads();

    for (int s = 0; s < 36; ++s) {
        const int cbuf = s & 1;
        if (s + 1 < 36) {
            BLOAD(s + 1);                       // vmcnt pending across this step
            LOAD_A32((s + 1) * 64,      b0, b1);
            LOAD_A32((s + 1) * 64 + 32, b2, b3);
        }
        // substep 0 (k 0..31): A regs from previous step (latency already covered)
        {
            CVT_AB(a0, a1, fah, fal);
            const int rb = cbuf * 4096 + lq * 512 + l15 * 8;
#pragma unroll
            for (int ct = 0; ct < 4; ++ct) {
                short8 fbh = *(const short8*)&Bh[rb + ct * 128];
                short8 fbl = *(const short8*)&Bl[rb + ct * 128];
                acc[ct] = __builtin_amdgcn_mfma_f32_16x16x32_bf16(fah, fbh, acc[ct], 0, 0, 0);
                acc[ct] = __builtin_amdgcn_mfma_f32_16x16x32_bf16(fah, fbl, acc[ct], 0, 0, 0);
                acc[ct] = __builtin_amdgcn_mfma_f32_16x16x32_bf16(fal, fbh, acc[ct], 0, 0, 0);
            }
        }
        // substep 1 (k 32..63)
        {
            CVT_AB(a2, a3, fah, fal);
            const int rb = cbuf * 4096 + (4 + lq) * 512 + l15 * 8;
#pragma unroll
            for (int ct = 0; ct < 4; ++ct) {
                short8 fbh = *(const short8*)&Bh[rb + ct * 128];
                short8 fbl = *(const short8*)&Bl[rb + ct * 128];
                acc[ct] = __builtin_amdgcn_mfma_f32_16x16x32_bf16(fah, fbh, acc[ct], 0, 0, 0);
                acc[ct] = __builtin_amdgcn_mfma_f32_16x16x32_bf16(fah, fbl, acc[ct], 0, 0, 0);
                acc[ct] = __builtin_amdgcn_mfma_f32_16x16x32_bf16(fal, fbh, acc[ct], 0, 0, 0);
            }
        }
        if (s + 1 < 36) BSTORE(cbuf ^ 1);       // waits vmcnt(rh/rl) only; A stays in flight
        __syncthreads();                        // lgkm drain only (no global_load_lds)
        a0 = b0; a1 = b1; a2 = b2; a3 = b3;
    }
#undef BLOAD
#undef BSTORE
#undef LOAD_A32
#undef CVT_AB

    // C/D: col(e) = lane&15, row(m) = (lane>>4)*4 + reg  [m89]
    const int rbase = m0 + w * 16 + lq * 4;
    float rsum[4] = {0.f, 0.f, 0.f, 0.f};
#pragma unroll
    for (int ct = 0; ct < 4; ++ct) {
        int e = e0 + ct * 16 + l15;
        float bias = cbias[e];
#pragma unroll
        for (int r = 0; r < 4; ++r) {
            float vv = fmaxf(acc[ct][r] + bias, 0.f);
            outB[(size_t)(rbase + r) * 256 + e] = f2bf(vv);
            rsum[r] += vv;
        }
    }
    if (m0 < NTOK) {   // batch-0 block: emit 64-e partial sum for the byte path
#pragma unroll
        for (int r = 0; r < 4; ++r) {
            float sv = rsum[r];
            sv += __shfl_xor(sv, 1); sv += __shfl_xor(sv, 2);
            sv += __shfl_xor(sv, 4); sv += __shfl_xor(sv, 8);
            if (l15 == 0) tokmean4[(size_t)eb * NTOK + rbase + r] = sv;
        }
    }
}

// ---------- bf16 MFMA GEMM, K=256, 2-phase staging, XCD swizzle (784 blocks) ----------
// C[m,e] = sum_k A[m,k]*W[e,k] + bias[e] (+addvec[e]) (mask m%NTOK >= *Sptr -> 0)
__global__ __launch_bounds__(256) void gemm_single_k(
    const unsigned short* __restrict__ A, const unsigned short* __restrict__ W,
    const float* __restrict__ bias, const float* __restrict__ addvec,
    const int* __restrict__ Sptr, float* __restrict__ outF, unsigned short* __restrict__ outB)
{
    __shared__ __align__(16) unsigned short As[8192], Bs[8192];   // 16 KB + 16 KB
    const int t = threadIdx.x, lane = t & 63, w = t >> 6;
    const int v_ = blockIdx.x;
    const int s_ = (v_ & 7) * 98 + (v_ >> 3);          // 784 = 8*98
    const int m0 = (s_ >> 2) * 64, e0 = (s_ & 3) * 64;
    const int l15 = lane & 15, lq = lane >> 4;
    const unsigned short* ga = A + (size_t)(m0 + lane) * 256;
    const unsigned short* gb = W + (size_t)(e0 + lane) * 256;
    // phase 1: kg 0..15
#pragma unroll
    for (int kg = w; kg < 16; kg += 4) {
        async16(ga + kg * 8, &As[kg * 512]);
        async16(gb + kg * 8, &Bs[kg * 512]);
    }
    f32x4 acc[4] = {};
    __syncthreads();
#pragma unroll
    for (int s = 0; s < 4; ++s) {
        int kg = s * 4 + lq;
        short8 a = *(const short8*)&As[kg * 512 + (w * 16 + l15) * 8];
#pragma unroll
        for (int ct = 0; ct < 4; ++ct) {
            short8 bb = *(const short8*)&Bs[kg * 512 + (ct * 16 + l15) * 8];
            acc[ct] = __builtin_amdgcn_mfma_f32_16x16x32_bf16(a, bb, acc[ct], 0, 0, 0);
        }
    }
    __syncthreads();           // reads of phase 1 done; safe to overwrite
    // phase 2: kg 16..31 into same buffers
#pragma unroll
    for (int kg = w; kg < 16; kg += 4) {
        async16(ga + (16 + kg) * 8, &As[kg * 512]);
        async16(gb + (16 + kg) * 8, &Bs[kg * 512]);
    }
    __syncthreads();
#pragma unroll
    for (int s = 0; s < 4; ++s) {
        int kg = s * 4 + lq;
        short8 a = *(const short8*)&As[kg * 512 + (w * 16 + l15) * 8];
#pragma unroll
        for (int ct = 0; ct < 4; ++ct) {
            short8 bb = *(const short8*)&Bs[kg * 512 + (ct * 16 + l15) * 8];
            acc[ct] = __builtin_amdgcn_mfma_f32_16x16x32_bf16(a, bb, acc[ct], 0, 0, 0);
        }
    }
    int S = Sptr ? *Sptr : 0x7fffffff;
    int rbase = m0 + w * 16 + lq * 4;
#pragma unroll
    for (int ct = 0; ct < 4; ++ct) {
        int e = e0 + ct * 16 + l15;
        float bv = bias[e] + (addvec ? addvec[e] : 0.f);
#pragma unroll
        for (int r = 0; r < 4; ++r) {
            int mm = rbase + r;
            float vv = acc[ct][r] + bv;
            if ((mm % NTOK) >= S) vv = 0.f;
            size_t off = (size_t)mm * 256 + e;
            if (outF) outF[off] = vv;
            if (outB) outB[off] = f2bf(vv);
        }
    }
}

// ---------- fused dual GEMM (1568 blocks); optional scores epilogue for half 0 ----------
// If qp != nullptr: half-0 tiles are heads of kp -> compute scores directly
// (sc[(b*4+h)*NTOK+n] = sum_e kp[n,e]*qp[e], fp32 kp) and skip the kp write.
__global__ __launch_bounds__(256) void gemm_dual_k(
    const unsigned short* __restrict__ A0, const unsigned short* __restrict__ A1,
    const unsigned short* __restrict__ W,
    const float* __restrict__ bias0, const float* __restrict__ bias1,
    unsigned short* __restrict__ outB0, unsigned short* __restrict__ outB1,
    const float* __restrict__ qp, float* __restrict__ sc)
{
    __shared__ __align__(16) unsigned short As[8192], Bs[8192];
    const int t = threadIdx.x, lane = t & 63, w = t >> 6;
    const int v_ = blockIdx.x;
    const int s_ = (v_ & 7) * 196 + (v_ >> 3);         // 1568 = 8*196
    const int mb = s_ >> 3, ebg = s_ & 7;              // ebg 0..7 over 512 W rows
    const int half = ebg >> 2;
    const unsigned short* A = half ? A1 : A0;
    const float* bias = half ? bias1 : bias0;
    unsigned short* outB = half ? outB1 : outB0;
    const int m0 = mb * 64, eg0 = ebg * 64, el0 = (ebg & 3) * 64;
    const int l15 = lane & 15, lq = lane >> 4;
    const unsigned short* ga = A + (size_t)(m0 + lane) * 256;
    const unsigned short* gb = W + (size_t)(eg0 + lane) * 256;
#pragma unroll
    for (int kg = w; kg < 16; kg += 4) {
        async16(ga + kg * 8, &As[kg * 512]);
        async16(gb + kg * 8, &Bs[kg * 512]);
    }
    f32x4 acc[4] = {};
    __syncthreads();
#pragma unroll
    for (int s = 0; s < 4; ++s) {
        int kg = s * 4 + lq;
        short8 a = *(const short8*)&As[kg * 512 + (w * 16 + l15) * 8];
#pragma unroll
        for (int ct = 0; ct < 4; ++ct) {
            short8 bb = *(const short8*)&Bs[kg * 512 + (ct * 16 + l15) * 8];
            acc[ct] = __builtin_amdgcn_mfma_f32_16x16x32_bf16(a, bb, acc[ct], 0, 0, 0);
        }
    }
    __syncthreads();
#pragma unroll
    for (int kg = w; kg < 16; kg += 4) {
        async16(ga + (16 + kg) * 8, &As[kg * 512]);
        async16(gb + (16 + kg) * 8, &Bs[kg * 512]);
    }
    __syncthreads();
#pragma unroll
    for (int s = 0; s < 4; ++s) {
        int kg = s * 4 + lq;
        short8 a = *(const short8*)&As[kg * 512 + (w * 16 + l15) * 8];
#pragma unroll
        for (int ct = 0; ct < 4; ++ct) {
            short8 bb = *(const short8*)&Bs[kg * 512 + (ct * 16 + l15) * 8];
            acc[ct] = __builtin_amdgcn_mfma_f32_16x16x32_bf16(a, bb, acc[ct], 0, 0, 0);
        }
    }
    int rbase = m0 + w * 16 + lq * 4;
    if (qp && half == 0) {
        // scores epilogue: this tile is head h = ebg for 64 m-rows; kp stays in regs
        float sp[4] = {0.f, 0.f, 0.f, 0.f};
#pragma unroll
        for (int ct = 0; ct < 4; ++ct) {
            int e = el0 + ct * 16 + l15;
            float bv = bias[e];
            float qv = qp[e];
#pragma unroll
            for (int r = 0; r < 4; ++r) sp[r] += (acc[ct][r] + bv) * qv;
        }
#pragma unroll
        for (int r = 0; r < 4; ++r) {
            sp[r] += __shfl_xor(sp[r], 1); sp[r] += __shfl_xor(sp[r], 2);
            sp[r] += __shfl_xor(sp[r], 4); sp[r] += __shfl_xor(sp[r], 8);
        }
        if (l15 == 0) {
#pragma unroll
            for (int r = 0; r < 4; ++r) {
                int mm = rbase + r;
                int bb = mm / NTOK, nn = mm % NTOK;
                sc[(bb * 4 + ebg) * NTOK + nn] = sp[r];
            }
        }
    } else {
#pragma unroll
        for (int ct = 0; ct < 4; ++ct) {
            int e = el0 + ct * 16 + l15;
            float bv = bias[e];
#pragma unroll
            for (int r = 0; r < 4; ++r) {
                float vv = acc[ct][r] + bv;
                outB[(size_t)(rbase + r) * 256 + e] = f2bf(vv);
            }
        }
    }
}

// ---------- tokmean4 -> byte -> entropy -> boundary (b=0 only) ----------
__global__ __launch_bounds__(256) void boundary_k(
    const float* __restrict__ tokmean4, const float* __restrict__ ent_table,
    int* __restrict__ boundary)
{
    int n    = blockIdx.x * 4 + (threadIdx.x >> 6);
    int lane = threadIdx.x & 63;
    float s0 = tokmean4[n];
    float s1 = tokmean4[NTOK + n];
    float s2 = tokmean4[2 * NTOK + n];
    float s3 = tokmean4[3 * NTOK + n];
    float mean = ((s0 + s1) + (s2 + s3)) * (1.f / 256.f);   // deterministic order
    float bf = rintf(mean * 255.f);
    bf = fminf(fmaxf(bf, 0.f), 255.f);
    int byte = (int)bf;
    const float4 lg = reinterpret_cast<const float4*>(ent_table + byte * 256)[lane];
    float mx = wmax(fmaxf(fmaxf(lg.x, lg.y), fmaxf(lg.z, lg.w)));
    float e0 = expf(lg.x - mx), e1 = expf(lg.y - mx), e2 = expf(lg.z - mx), e3 = expf(lg.w - mx);
    float z = wsum(e0 + e1 + e2 + e3);
    float iz = 1.f / z;
    float p0 = e0 * iz, p1 = e1 * iz, p2 = e2 * iz, p3 = e3 * iz;
    float ep = -(p0 * log2f(p0 + 1e-9f) + p1 * log2f(p1 + 1e-9f) +
                 p2 * log2f(p2 + 1e-9f) + p3 * log2f(p3 + 1e-9f));
    ep = wsum(ep);
    if (lane == 0) boundary[n] = (ep > THRESH) ? 1 : 0;
}

// ---------- single-block scan: boundary -> seg_start[], S ----------
__global__ __launch_bounds__(256) void scan_k(const int* __restrict__ boundary,
    int* __restrict__ seg_start, int* __restrict__ Sptr)
{
    __shared__ int sums[256];
    const int t = threadIdx.x;
    const int CH = 13;
    int base = t * CH;
    int s = 0;
    for (int i = 0; i < CH; i++) { int n = base + i; if (n < NTOK) s += boundary[n]; }
    sums[t] = s; __syncthreads();
    for (int o = 1; o < 256; o <<= 1) {
        int v = sums[t];
        int u = (t >= o) ? sums[t - o] : 0;
        __syncthreads();
        sums[t] = v + u;
        __syncthreads();
    }
    int run = (t == 0) ? 0 : sums[t - 1];
    if (t == 0) seg_start[0] = 0;
    for (int i = 0; i < CH; i++) {
        int n = base + i;
        if (n >= NTOK) break;
        int v = boundary[n];
        if (n == NTOK - 1) { Sptr[0] = run + 1; seg_start[run + 1] = NTOK; }
        if (v && (n + 1 < NTOK)) seg_start[run + 1] = n + 1;
        run += v;
    }
}

// ---------- fused dual LayerNorm: bf16 in -> bf16 out; rows [0,MT) = K, [MT,2MT) = V ----------
__global__ __launch_bounds__(256) void lnKV_k(
    const unsigned short* __restrict__ Pk, const unsigned short* __restrict__ Pv,
    const float* __restrict__ gk, const float* __restrict__ bk,
    const float* __restrict__ gv, const float* __restrict__ bv,
    unsigned short* __restrict__ Yk, unsigned short* __restrict__ Yv)
{
    int row  = blockIdx.x * 4 + (threadIdx.x >> 6);   // 0..2*MT-1
    int lane = threadIdx.x & 63;
    int half = row >= MT;
    int r    = half ? row - MT : row;
    const unsigned short* X = half ? Pv : Pk;
    const float* g = half ? gv : gk;
    const float* b = half ? bv : bk;
    unsigned short* Y = half ? Yv : Yk;
    ushort4 xr = reinterpret_cast<const ushort4*>(X + (size_t)r * 256)[lane];
    float x0 = bf2f(xr.x), x1 = bf2f(xr.y), x2 = bf2f(xr.z), x3 = bf2f(xr.w);
    float m = wsum(x0 + x1 + x2 + x3) * (1.f / 256.f);
    float d0 = x0 - m, d1 = x1 - m, d2 = x2 - m, d3 = x3 - m;
    float var = wsum(d0 * d0 + d1 * d1 + d2 * d2 + d3 * d3) * (1.f / 256.f);
    float inv = 1.f / sqrtf(var + LN_EPS);
    float4 g4 = reinterpret_cast<const float4*>(g)[lane];
    float4 b4 = reinterpret_cast<const float4*>(b)[lane];
    ushort4 y;
    y.x = f2bf(d0 * inv * g4.x + b4.x);
    y.y = f2bf(d1 * inv * g4.y + b4.y);
    y.z = f2bf(d2 * inv * g4.z + b4.z);
    y.w = f2bf(d3 * inv * g4.w + b4.w);
    reinterpret_cast<ushort4*>(Y + (size_t)r * 256)[lane] = y;
}

// ---------- segment softmax-attention; block = (segment, batch), wave = head ----------
__global__ __launch_bounds__(256) void attn_bf_k(const float* __restrict__ sc,
    const unsigned short* __restrict__ vp, const int* __restrict__ seg_start,
    const int* __restrict__ Sptr, unsigned short* __restrict__ attn)
{
    int s    = blockIdx.x;
    int b    = blockIdx.y;
    int h    = threadIdx.x >> 6;
    int lane = threadIdx.x & 63;
    unsigned short* orow = attn + ((size_t)b * NTOK + s) * 256;
    int S = *Sptr;
    if (s >= S) { orow[h * 64 + lane] = 0; return; }
    int st = seg_start[s], en = seg_start[s + 1];
    const float* scr = sc + (b * 4 + h) * NTOK;
    float m = -1e30f;
    for (int n = st; n < en; n++) m = fmaxf(m, scr[n]);
    float den = 0.f, acc = 0.f;
    const unsigned short* vpb = vp + (size_t)b * NTOK * 256 + h * 64 + lane;
    for (int n = st; n < en; n++) {
        float wgt = expf(scr[n] - m);
        den += wgt;
        acc += wgt * bf2f(vpb[(size_t)n * 256]);
    }
    orow[h * 64 + lane] = f2bf(acc / den);
}

extern "C" void kernel_launch(void* const* d_in, const int* in_sizes, int n_in,
                              void* d_out, int out_size, void* d_ws, size_t ws_size,
                              hipStream_t stream)
{
    const float* video      = (const float*)d_in[0];
    const float* conv_w     = (const float*)d_in[1];
    const float* conv_b     = (const float*)d_in[2];
    const float* wq_w       = (const float*)d_in[3];
    const float* wq_b       = (const float*)d_in[4];
    const float* wk_w       = (const float*)d_in[5];
    const float* wk_b       = (const float*)d_in[6];
    const float* wv_w       = (const float*)d_in[7];
    const float* wv_b       = (const float*)d_in[8];
    const float* lnq_g      = (const float*)d_in[9];
    const float* lnq_b      = (const float*)d_in[10];
    const float* lnk_g      = (const float*)d_in[11];
    const float* lnk_b      = (const float*)d_in[12];
    const float* lnv_g      = (const float*)d_in[13];
    const float* lnv_b      = (const float*)d_in[14];
    const float* in_proj_w  = (const float*)d_in[15];
    const float* in_proj_b  = (const float*)d_in[16];
    const float* out_proj_w = (const float*)d_in[17];
    const float* out_proj_b = (const float*)d_in[18];
    const float* dense_w    = (const float*)d_in[19];
    const float* dense_b    = (const float*)d_in[20];
    const float* bproj_w    = (const float*)d_in[21];
    const float* bproj_b    = (const float*)d_in[22];
    const float* group_q    = (const float*)d_in[23];
    const float* ent_table  = (const float*)d_in[24];
    float* out = (float*)d_out;

    // ---- workspace layout (~48.7 MB) ----
    float* tokmean4 = (float*)d_ws;                      // 4*NTOK floats (+pad to 16384)
    unsigned short* Pk  = (unsigned short*)(tokmean4 + 16384);   // pre-LN K (bf16)
    unsigned short* Pv  = Pk  + (size_t)MT * 256;        // pre-LN V (bf16)
    unsigned short* B1  = Pv  + (size_t)MT * 256;        // tokens / attn-out
    unsigned short* B2k = B1  + (size_t)MT * 256;        // kln / o1
    unsigned short* B2v = B2k + (size_t)MT * 256;        // vln / o2
    unsigned short* B3v = B2v + (size_t)MT * 256;        // vp
    unsigned short* cwh = B3v + (size_t)MT * 256;        // conv weights hi (permuted)
    unsigned short* cwl = cwh + 256 * KCV;               // conv weights lo (permuted)
    unsigned short* wpool = cwl + 256 * KCV;             // 524288 bf16 weights
    float* sc = (float*)(wpool + 524288);                // scores [B*NH][NTOK]
    float* qp = sc + 16 * NTOK;
    int* boundary  = (int*)(qp + 256);
    int* seg_start = boundary + NTOK;
    int* Sp        = seg_start + (NTOK + 1);

    const unsigned short* inpb   = wpool + 131072;       // 3E x E
    const unsigned short* outpb  = wpool + 327680;
    const unsigned short* denseb = wpool + 393216;
    const unsigned short* bprojb = wpool + 458752;

    dim3 blk(256);
    // prep: split_cw (288) + cast_w (2048) + query (1)
    prep_k<<<dim3(2337), blk, 0, stream>>>(conv_w, cwh, cwl,
                                           wk_w, wv_w, in_proj_w, out_proj_w,
                                           dense_w, bproj_w, wpool,
                                           group_q, wq_w, wq_b, lnq_g, lnq_b,
                                           in_proj_w, in_proj_b, qp);
    conv_mfma_k<<<dim3(784), blk, 0, stream>>>(video, cwh, cwl, conv_b, tokmean4, B1);
    boundary_k<<<dim3(NTOK / 4), blk, 0, stream>>>(tokmean4, ent_table, boundary);
    scan_k<<<dim3(1), blk, 0, stream>>>(boundary, seg_start, Sp);
    // fused K+V pre-LN GEMM: W rows 0..255 = wk, 256..511 = wv (contiguous in pool)
    gemm_dual_k<<<dim3(1568), blk, 0, stream>>>(B1, B1, wpool, wk_b, wv_b, Pk, Pv,
                                                nullptr, nullptr);
    // fused K+V LayerNorm
    lnKV_k<<<dim3(2 * MT / 4), blk, 0, stream>>>(Pk, Pv, lnk_g, lnk_b, lnv_g, lnv_b,
                                                 B2k, B2v);
    // fused kp+vp projection; kp half computes scores in epilogue (kp never stored)
    gemm_dual_k<<<dim3(1568), blk, 0, stream>>>(B2k, B2v, inpb + 65536,
                                                in_proj_b + 256, in_proj_b + 512,
                                                nullptr, B3v, qp, sc);
    // segment attention: block = (segment, batch), 4 waves = 4 heads
    attn_bf_k<<<dim3(NTOK, 4), blk, 0, stream>>>(sc, B3v, seg_start, Sp, B1);
    // tail projections
    gemm_single_k<<<dim3(784), blk, 0, stream>>>(B1, outpb, out_proj_b,
                                                 nullptr, nullptr, nullptr, B2k);
    gemm_single_k<<<dim3(784), blk, 0, stream>>>(B2k, denseb, dense_b,
                                                 group_q, nullptr, nullptr, B2v);
    gemm_single_k<<<dim3(784), blk, 0, stream>>>(B2v, bprojb, bproj_b,
                                                 nullptr, Sp, out, nullptr);
}